// Round 16
// baseline (347.784 us; speedup 1.0000x reference)
//
#include <hip/hip_runtime.h>
#include <math.h>

#define BB 8
#define NN 8192
#define CC 64
#define FE 32
#define KN 16
#define CP3 67
#define QPW 8                 // queries per wave (z-adjacent group)
#define WPB 4                 // waves per block (one group per z-rank quartile)
#define CAPQ 64               // per-query stack (count-checked => exact)
#define ZBINS 256

// Device-global scratch (module .bss). All bytes written every launch before read.
__device__ float g_wsf[128];                  // scale[64], shift[64]
__device__ float g_feat0[BB * NN * FE];       // 8 MB
__device__ int   g_idx[BB * NN * KN];         // 4 MB
__device__ float4 g_sorted[BB * NN];          // z-bin-sorted {x,y,z,xx}
__device__ int    g_sorig[BB * NN];           // sorted -> original index
__device__ unsigned g_binoff[BB * (ZBINS + 1)];

// Identical in k_zbin and k_knn (same source => same bits; monotone in z).
__device__ __forceinline__ int zbin(float z) {
    int bi = (int)((z + 6.0f) * (64.0f / 3.0f));   // 256 bins over [-6,6]
    if (bi < 0) bi = 0;
    if (bi > ZBINS - 1) bi = ZBINS - 1;
    return bi;
}
// FROZEN reference xx (verified R5, XLA-CPU FMA contraction)
__device__ __forceinline__ float frz_xx(float x, float y, float z) {
    return __fmaf_rn(z, z, __fmaf_rn(y, y, __fmul_rn(x, x)));
}

// ---------------- kernel 1: BN stats -> scale/shift ----------------
__global__ __launch_bounds__(1024) void k_bnstats(const float* __restrict__ feat,
        const float* __restrict__ gamma, const float* __restrict__ beta) {
    int c = blockIdx.x;
    int tid = threadIdx.x;
    double s = 0.0, s2 = 0.0;
    for (int b = 0; b < BB; ++b) {
        const float* p = feat + ((size_t)(b * CC + c)) * NN;
        for (int n = tid; n < NN; n += 1024) {
            double v = (double)p[n];
            s += v; s2 += v * v;
        }
    }
    __shared__ double sh[1024], sh2[1024];
    sh[tid] = s; sh2[tid] = s2;
    __syncthreads();
    for (int off = 512; off > 0; off >>= 1) {
        if (tid < off) { sh[tid] += sh[tid + off]; sh2[tid] += sh2[tid + off]; }
        __syncthreads();
    }
    if (tid == 0) {
        double inv = 1.0 / (double)(BB * NN);
        double mean = sh[0] * inv;
        double var = sh2[0] * inv - mean * mean;
        float sc = gamma[c] * (float)(1.0 / sqrt(var + (double)1e-5f));
        g_wsf[c] = sc;
        g_wsf[64 + c] = beta[c] - sc * (float)mean;
    }
}

// ---------------- kernel 1b: z-binning (histogram + scatter) --------------
__global__ __launch_bounds__(1024) void k_zbin(const float* __restrict__ xyz) {
    __shared__ unsigned hist[ZBINS];
    __shared__ unsigned boff[ZBINS + 1];
    int b = blockIdx.x;
    int tid = threadIdx.x;
    if (tid < ZBINS) hist[tid] = 0;
    __syncthreads();
    const float* bx = xyz + (size_t)b * NN * 3;
    for (int n = tid; n < NN; n += 1024)
        atomicAdd(&hist[zbin(bx[n * 3 + 2])], 1u);
    __syncthreads();
    if (tid == 0) {
        unsigned s = 0;
        for (int i = 0; i < ZBINS; ++i) { boff[i] = s; s += hist[i]; }
        boff[ZBINS] = s;
    }
    __syncthreads();
    if (tid < ZBINS) hist[tid] = 0;            // reuse as cursors
    if (tid < ZBINS + 1) g_binoff[b * (ZBINS + 1) + tid] = boff[tid];
    __syncthreads();
    for (int n = tid; n < NN; n += 1024) {
        const float* p = bx + (size_t)n * 3;
        float x = p[0], y = p[1], z = p[2];
        unsigned pos = boff[zbin(z)] + atomicAdd(&hist[zbin(z)], 1u);
        g_sorted[(size_t)b * NN + pos] = make_float4(x, y, z, frz_xx(x, y, z));
        g_sorig[(size_t)b * NN + pos] = n;
    }
}

// ---------------- kernel 2: feat0 = Wg' * [feat;xyz] + bias0 ----------------
__global__ __launch_bounds__(256) void k_feat0(const float* __restrict__ feat,
        const float* __restrict__ xyz, const float* __restrict__ Wg) {
    __shared__ float wgs[CP3 * FE];
    __shared__ float bias0[FE];
    int tid = threadIdx.x;
    for (int i = tid; i < CP3 * FE; i += 256) {
        int c = i >> 5, e = i & 31;
        float w = Wg[e * CP3 + c];
        if (c < CC) w *= g_wsf[c];
        wgs[c * FE + e] = w;
    }
    if (tid < FE) {
        float sacc = 0.f;
        for (int c = 0; c < CC; ++c) sacc = fmaf(Wg[tid * CP3 + c], g_wsf[64 + c], sacc);
        bias0[tid] = sacc;
    }
    __syncthreads();
    int b = blockIdx.x >> 5;
    int n = ((blockIdx.x & 31) << 8) + tid;
    const float* pz = xyz + ((size_t)(b * NN + n)) * 3;
    float x = pz[0], y = pz[1], z = pz[2];

    float acc[FE];
    #pragma unroll
    for (int e = 0; e < FE; ++e) acc[e] = bias0[e];
    const float* fp = feat + (size_t)b * CC * NN + n;
    for (int c = 0; c < CC; ++c) {
        float v = fp[(size_t)c * NN];
        const float4* w4 = (const float4*)(wgs + c * FE);
        #pragma unroll
        for (int e0 = 0; e0 < 8; ++e0) {
            float4 w = w4[e0];
            acc[e0 * 4 + 0] = fmaf(w.x, v, acc[e0 * 4 + 0]);
            acc[e0 * 4 + 1] = fmaf(w.y, v, acc[e0 * 4 + 1]);
            acc[e0 * 4 + 2] = fmaf(w.z, v, acc[e0 * 4 + 2]);
            acc[e0 * 4 + 3] = fmaf(w.w, v, acc[e0 * 4 + 3]);
        }
    }
    #pragma unroll
    for (int d = 0; d < 3; ++d) {
        float v = (d == 0) ? x : ((d == 1) ? y : z);
        const float4* w4 = (const float4*)(wgs + (CC + d) * FE);
        #pragma unroll
        for (int e0 = 0; e0 < 8; ++e0) {
            float4 w = w4[e0];
            acc[e0 * 4 + 0] = fmaf(w.x, v, acc[e0 * 4 + 0]);
            acc[e0 * 4 + 1] = fmaf(w.y, v, acc[e0 * 4 + 1]);
            acc[e0 * 4 + 2] = fmaf(w.z, v, acc[e0 * 4 + 2]);
            acc[e0 * 4 + 3] = fmaf(w.w, v, acc[e0 * 4 + 3]);
        }
    }
    float4* outp = (float4*)(g_feat0 + ((size_t)(b * NN + n)) * FE);
    #pragma unroll
    for (int e0 = 0; e0 < 8; ++e0)
        outp[e0] = make_float4(acc[e0 * 4 + 0], acc[e0 * 4 + 1], acc[e0 * 4 + 2], acc[e0 * 4 + 3]);
}

// ---------------- kernel 3: quartile-stratified shared-window KNN ---------
// FROZEN reference arithmetic (verified R5):
//   dot  = fma(zq,zm, fma(yq,ym, xq*xm))
//   dist = fadd( fma(-2, dot, xx_q), xx_m )
// R16 = R13's shared-window scan (each 64-cand load serves 8 z-adjacent
// queries -> ~5 essential VALU/query-eval) + R15's stratification lesson,
// applied at the wave-in-block level: block beta carries 4 waves, wave w
// takes group (w*256 + beta) -- one group per z-rank QUARTILE. Per-block
// work ~ sum of 4 quartile samples ~ uniform => no drain tail (R13's 19%
// occupancy), while adjacent blocks keep adjacent windows (locality).
// Exactness machinery unchanged & proven: gate+count-check (16<=cnt<=64),
// bracketed geometric bisection (R12), counting-rank selection (R13),
// SO[] loaded only for passers (R15).
__global__ __launch_bounds__(256) void k_knn() {
    __shared__ unsigned long long qbuf[WPB * QPW * CAPQ];   // 16 KB
    int tid = threadIdx.x;
    int lane = tid & 63;
    int w = tid >> 6;
    int b = blockIdx.x >> 8;                    // 256 blocks per batch
    int beta = blockIdx.x & 255;
    int group = (w << 8) + beta;                // quartile w, groups 0..1023
    int n0 = group * QPW;
    const float4* S = g_sorted + (size_t)b * NN;
    const int* SO = g_sorig + (size_t)b * NN;
    const unsigned* BO = g_binoff + b * (ZBINS + 1);
    unsigned long long lt = (1ull << lane) - 1ull;

    float qx[QPW], qy[QPW], qz[QPW], qxx[QPW], t0[QPW], tlo[QPW], thi[QPW];
    int qorig[QPW];
    unsigned cnt[QPW];
    bool qdone[QPW];
    #pragma unroll
    for (int i = 0; i < QPW; ++i) {
        float4 qv = S[n0 + i];
        qx[i] = qv.x; qy[i] = qv.y; qz[i] = qv.z; qxx[i] = qv.w;
        qorig[i] = SO[n0 + i];
        float tt = 0.053f * __expf(qxx[i] * (1.0f / 3.0f));  // ~32 expected passers
        t0[i] = tt > 3.f ? 3.f : tt;
        tlo[i] = 0.f; thi[i] = 0.f;             // 0 = unset bracket ends
        cnt[i] = 0;
        qdone[i] = false;
    }

    for (int attempt = 0; attempt < 40; ++attempt) {
        // wave-private window over active queries (uniform arithmetic)
        float zlo = 1e30f, zhi = -1e30f;
        bool anyact = false;
        #pragma unroll
        for (int i = 0; i < QPW; ++i) {
            if (qdone[i]) continue;
            anyact = true;
            float R = __fsqrt_rn(t0[i] + 1e-3f) + 1e-3f;
            zlo = fminf(zlo, qz[i] - R);
            zhi = fmaxf(zhi, qz[i] + R);
        }
        if (!anyact) break;
        int blo = zbin(zlo) - 1; if (blo < 0) blo = 0;
        int bhi = zbin(zhi) + 1; if (bhi > ZBINS - 1) bhi = ZBINS - 1;
        int lo = (int)BO[blo];
        int hi = (int)BO[bhi + 1];

        for (int p = lo; p < hi; p += 64) {
            int jj = p + lane;
            bool inb = jj < hi;
            int j = inb ? jj : hi - 1;
            float4 cc = S[j];
            #pragma unroll
            for (int i = 0; i < QPW; ++i) {
                if (qdone[i]) continue;                       // uniform branch
                float dot = __fmaf_rn(qz[i], cc.z, __fmaf_rn(qy[i], cc.y, __fmul_rn(qx[i], cc.x)));
                float dist = __fadd_rn(__fmaf_rn(-2.f, dot, qxx[i]), cc.w);
                bool pr = (dist <= t0[i]) && inb;
                unsigned long long mask = __ballot(pr);
                if (mask) {
                    unsigned pos = cnt[i] + (unsigned)__popcll(mask & lt);
                    if (pr && pos < CAPQ) {
                        int corig = SO[j];      // loaded only for passers
                        int db = __float_as_int(dist);
                        unsigned key = (unsigned)db ^ (unsigned)((db >> 31) | 0x80000000);
                        qbuf[(w * QPW + i) * CAPQ + pos] =
                            ((unsigned long long)key << 32) | (unsigned)corig;
                    }
                    cnt[i] += (unsigned)__popcll(mask);
                }
            }
        }
        #pragma unroll
        for (int i = 0; i < QPW; ++i) {
            if (qdone[i]) continue;
            if (cnt[i] < KN) {
                tlo[i] = t0[i];
                t0[i] = (thi[i] > 0.f) ? __fsqrt_rn(tlo[i] * thi[i]) : t0[i] * 2.0f;
                cnt[i] = 0;
            } else if (cnt[i] > CAPQ) {
                thi[i] = t0[i];
                t0[i] = (tlo[i] > 0.f) ? __fsqrt_rn(tlo[i] * thi[i]) : t0[i] * 0.5f;
                cnt[i] = 0;
            } else {
                qdone[i] = true; t0[i] = -1.0e30f;           // freeze stack
            }
        }
    }

    // ---- selection: counting-rank over the stack (no shuffle chains) ----
    #pragma unroll
    for (int i = 0; i < QPW; ++i) {
        unsigned tot = cnt[i] > CAPQ ? CAPQ : cnt[i];
        const unsigned long long* pb = qbuf + (w * QPW + i) * CAPQ;
        unsigned long long e0 = ((unsigned)lane < tot) ? pb[lane] : ~0ull;
        unsigned rank0 = 0;
        for (unsigned jx = 0; jx < tot; ++jx) {
            unsigned long long v = pb[jx];      // uniform addr -> LDS broadcast
            rank0 += (v < e0) ? 1u : 0u;
        }
        if (((unsigned)lane < tot) && rank0 < KN)
            g_idx[(b * NN + qorig[i]) * KN + rank0] = (int)(e0 & 0xffffffffull);
    }
}

// ---------------- kernel 4: gather+max, rel, out = Wh' * rel ----------------
__global__ __launch_bounds__(256) void k_out(const float* __restrict__ Wh,
        float* __restrict__ out) {
    __shared__ float whs[CC * FE];
    int tid = threadIdx.x;
    for (int i = tid; i < CC * FE; i += 256) {
        int c = i >> 5, e = i & 31;
        float s = 0.f;
        #pragma unroll
        for (int m = 0; m < 4; ++m) s += Wh[c * 128 + m * 32 + e];
        whs[i] = s;
    }
    __syncthreads();
    int b = blockIdx.x >> 5;
    int n = ((blockIdx.x & 31) << 8) + tid;
    const int* ip = g_idx + (size_t)(b * NN + n) * KN;
    const float4* f0 = (const float4*)(g_feat0 + (size_t)b * NN * FE);
    float gmax[FE];
    #pragma unroll
    for (int e = 0; e < FE; ++e) gmax[e] = -__builtin_inff();
    for (int k = 0; k < KN; ++k) {
        int id = ip[k] & (NN - 1);      // defensive mask, no-op for valid idx
        const float4* row = f0 + (size_t)id * 8;
        #pragma unroll
        for (int e0 = 0; e0 < 8; ++e0) {
            float4 v = row[e0];
            gmax[e0 * 4 + 0] = fmaxf(gmax[e0 * 4 + 0], v.x);
            gmax[e0 * 4 + 1] = fmaxf(gmax[e0 * 4 + 1], v.y);
            gmax[e0 * 4 + 2] = fmaxf(gmax[e0 * 4 + 2], v.z);
            gmax[e0 * 4 + 3] = fmaxf(gmax[e0 * 4 + 3], v.w);
        }
    }
    const float4* selfr = f0 + (size_t)n * 8;
    float rel[FE];
    #pragma unroll
    for (int e0 = 0; e0 < 8; ++e0) {
        float4 v = selfr[e0];
        rel[e0 * 4 + 0] = gmax[e0 * 4 + 0] - v.x;
        rel[e0 * 4 + 1] = gmax[e0 * 4 + 1] - v.y;
        rel[e0 * 4 + 2] = gmax[e0 * 4 + 2] - v.z;
        rel[e0 * 4 + 3] = gmax[e0 * 4 + 3] - v.w;
    }
    float* op = out + (size_t)b * CC * NN + n;
    for (int c = 0; c < CC; ++c) {
        const float4* w4 = (const float4*)(whs + c * FE);
        float s = 0.f;
        #pragma unroll
        for (int e0 = 0; e0 < 8; ++e0) {
            float4 w = w4[e0];
            s = fmaf(w.x, rel[e0 * 4 + 0], s);
            s = fmaf(w.y, rel[e0 * 4 + 1], s);
            s = fmaf(w.z, rel[e0 * 4 + 2], s);
            s = fmaf(w.w, rel[e0 * 4 + 3], s);
        }
        op[(size_t)c * NN] = s;
    }
}

extern "C" void kernel_launch(void* const* d_in, const int* in_sizes, int n_in,
                              void* d_out, int out_size, void* d_ws, size_t ws_size,
                              hipStream_t stream) {
    const float* xyz   = (const float*)d_in[0];
    const float* feat  = (const float*)d_in[1];
    const float* gamma = (const float*)d_in[2];
    const float* beta  = (const float*)d_in[3];
    const float* Wg    = (const float*)d_in[4];
    const float* Wh    = (const float*)d_in[5];
    float* out = (float*)d_out;
    (void)d_ws; (void)ws_size;

    hipLaunchKernelGGL(k_bnstats, dim3(64),   dim3(1024), 0, stream, feat, gamma, beta);
    hipLaunchKernelGGL(k_zbin,    dim3(8),    dim3(1024), 0, stream, xyz);
    hipLaunchKernelGGL(k_feat0,   dim3(256),  dim3(256),  0, stream, feat, xyz, Wg);
    hipLaunchKernelGGL(k_knn,     dim3(2048), dim3(256),  0, stream);
    hipLaunchKernelGGL(k_out,     dim3(256),  dim3(256),  0, stream, Wh, out);
}

// Round 17
// 277.661 us; speedup vs baseline: 1.2525x; 1.2525x over previous
//
#include <hip/hip_runtime.h>
#include <math.h>

#define BB 8
#define NN 8192
#define CC 64
#define FE 32
#define KN 16
#define CP3 67
#define WPB 4                 // waves per block
#define CAPQ 64               // per-query stack (count-checked => exact)
#define ZBINS 256

// Device-global scratch (module .bss). All bytes written every launch before read.
__device__ float g_wsf[128];                  // scale[64], shift[64]
__device__ float g_feat0[BB * NN * FE];       // 8 MB
__device__ int   g_idx[BB * NN * KN];         // 4 MB
__device__ float4 g_sorted[BB * NN];          // z-bin-sorted {x,y,z,xx}
__device__ int    g_sorig[BB * NN];           // sorted -> original index
__device__ unsigned g_binoff[BB * (ZBINS + 1)];

// Identical in k_zbin and k_knn (same source => same bits; monotone in z).
__device__ __forceinline__ int zbin(float z) {
    int bi = (int)((z + 6.0f) * (64.0f / 3.0f));   // 256 bins over [-6,6]
    if (bi < 0) bi = 0;
    if (bi > ZBINS - 1) bi = ZBINS - 1;
    return bi;
}
// FROZEN reference xx (verified R5, XLA-CPU FMA contraction)
__device__ __forceinline__ float frz_xx(float x, float y, float z) {
    return __fmaf_rn(z, z, __fmaf_rn(y, y, __fmul_rn(x, x)));
}

// ---------------- kernel 1: BN stats -> scale/shift ----------------
__global__ __launch_bounds__(1024) void k_bnstats(const float* __restrict__ feat,
        const float* __restrict__ gamma, const float* __restrict__ beta) {
    int c = blockIdx.x;
    int tid = threadIdx.x;
    double s = 0.0, s2 = 0.0;
    for (int b = 0; b < BB; ++b) {
        const float* p = feat + ((size_t)(b * CC + c)) * NN;
        for (int n = tid; n < NN; n += 1024) {
            double v = (double)p[n];
            s += v; s2 += v * v;
        }
    }
    __shared__ double sh[1024], sh2[1024];
    sh[tid] = s; sh2[tid] = s2;
    __syncthreads();
    for (int off = 512; off > 0; off >>= 1) {
        if (tid < off) { sh[tid] += sh[tid + off]; sh2[tid] += sh2[tid + off]; }
        __syncthreads();
    }
    if (tid == 0) {
        double inv = 1.0 / (double)(BB * NN);
        double mean = sh[0] * inv;
        double var = sh2[0] * inv - mean * mean;
        float sc = gamma[c] * (float)(1.0 / sqrt(var + (double)1e-5f));
        g_wsf[c] = sc;
        g_wsf[64 + c] = beta[c] - sc * (float)mean;
    }
}

// ---------------- kernel 1b: z-binning (histogram + scatter) --------------
__global__ __launch_bounds__(1024) void k_zbin(const float* __restrict__ xyz) {
    __shared__ unsigned hist[ZBINS];
    __shared__ unsigned boff[ZBINS + 1];
    int b = blockIdx.x;
    int tid = threadIdx.x;
    if (tid < ZBINS) hist[tid] = 0;
    __syncthreads();
    const float* bx = xyz + (size_t)b * NN * 3;
    for (int n = tid; n < NN; n += 1024)
        atomicAdd(&hist[zbin(bx[n * 3 + 2])], 1u);
    __syncthreads();
    if (tid == 0) {
        unsigned s = 0;
        for (int i = 0; i < ZBINS; ++i) { boff[i] = s; s += hist[i]; }
        boff[ZBINS] = s;
    }
    __syncthreads();
    if (tid < ZBINS) hist[tid] = 0;            // reuse as cursors
    if (tid < ZBINS + 1) g_binoff[b * (ZBINS + 1) + tid] = boff[tid];
    __syncthreads();
    for (int n = tid; n < NN; n += 1024) {
        const float* p = bx + (size_t)n * 3;
        float x = p[0], y = p[1], z = p[2];
        unsigned pos = boff[zbin(z)] + atomicAdd(&hist[zbin(z)], 1u);
        g_sorted[(size_t)b * NN + pos] = make_float4(x, y, z, frz_xx(x, y, z));
        g_sorig[(size_t)b * NN + pos] = n;
    }
}

// ---------------- kernel 2: feat0 = Wg' * [feat;xyz] + bias0 ----------------
__global__ __launch_bounds__(256) void k_feat0(const float* __restrict__ feat,
        const float* __restrict__ xyz, const float* __restrict__ Wg) {
    __shared__ float wgs[CP3 * FE];
    __shared__ float bias0[FE];
    int tid = threadIdx.x;
    for (int i = tid; i < CP3 * FE; i += 256) {
        int c = i >> 5, e = i & 31;
        float w = Wg[e * CP3 + c];
        if (c < CC) w *= g_wsf[c];
        wgs[c * FE + e] = w;
    }
    if (tid < FE) {
        float sacc = 0.f;
        for (int c = 0; c < CC; ++c) sacc = fmaf(Wg[tid * CP3 + c], g_wsf[64 + c], sacc);
        bias0[tid] = sacc;
    }
    __syncthreads();
    int b = blockIdx.x >> 5;
    int n = ((blockIdx.x & 31) << 8) + tid;
    const float* pz = xyz + ((size_t)(b * NN + n)) * 3;
    float x = pz[0], y = pz[1], z = pz[2];

    float acc[FE];
    #pragma unroll
    for (int e = 0; e < FE; ++e) acc[e] = bias0[e];
    const float* fp = feat + (size_t)b * CC * NN + n;
    for (int c = 0; c < CC; ++c) {
        float v = fp[(size_t)c * NN];
        const float4* w4 = (const float4*)(wgs + c * FE);
        #pragma unroll
        for (int e0 = 0; e0 < 8; ++e0) {
            float4 w = w4[e0];
            acc[e0 * 4 + 0] = fmaf(w.x, v, acc[e0 * 4 + 0]);
            acc[e0 * 4 + 1] = fmaf(w.y, v, acc[e0 * 4 + 1]);
            acc[e0 * 4 + 2] = fmaf(w.z, v, acc[e0 * 4 + 2]);
            acc[e0 * 4 + 3] = fmaf(w.w, v, acc[e0 * 4 + 3]);
        }
    }
    #pragma unroll
    for (int d = 0; d < 3; ++d) {
        float v = (d == 0) ? x : ((d == 1) ? y : z);
        const float4* w4 = (const float4*)(wgs + (CC + d) * FE);
        #pragma unroll
        for (int e0 = 0; e0 < 8; ++e0) {
            float4 w = w4[e0];
            acc[e0 * 4 + 0] = fmaf(w.x, v, acc[e0 * 4 + 0]);
            acc[e0 * 4 + 1] = fmaf(w.y, v, acc[e0 * 4 + 1]);
            acc[e0 * 4 + 2] = fmaf(w.z, v, acc[e0 * 4 + 2]);
            acc[e0 * 4 + 3] = fmaf(w.w, v, acc[e0 * 4 + 3]);
        }
    }
    float4* outp = (float4*)(g_feat0 + ((size_t)(b * NN + n)) * FE);
    #pragma unroll
    for (int e0 = 0; e0 < 8; ++e0)
        outp[e0] = make_float4(acc[e0 * 4 + 0], acc[e0 * 4 + 1], acc[e0 * 4 + 2], acc[e0 * 4 + 3]);
}

// ---------------- kernel 3: stratified pair-scan KNN ---------------------
// FROZEN reference arithmetic (verified R5):
//   dot  = fma(zq,zm, fma(yq,ym, xq*xm))
//   dist = fadd( fma(-2, dot, xx_q), xx_m )
// R17 = R15 (stratified autonomous waves: per-wave work spread over z-rank
// strata => near-uniform, no drain tail) + 2 z-adjacent queries evaluated
// per candidate load (pairs (2g,2g+1), strata pp*2048): halves scan steps
// and L2 traffic, ~doubles VALU per load -> fewer load-latency stalls.
// Proven machinery unchanged: gate+count-check (16<=cnt<=64), bracketed
// geometric bisection (R12), counting-rank selection (R13), SO[] only for
// passers (R15). Union pair-window covers each query's own gate set.
__global__ __launch_bounds__(256) void k_knn() {
    __shared__ unsigned long long qbuf[WPB * 2 * CAPQ];   // 4 KB
    int tid = threadIdx.x;
    int lane = tid & 63;
    int w = tid >> 6;
    int wid = blockIdx.x * WPB + w;             // 0..8191
    int b = wid >> 10;                          // 1024 waves per batch
    int g = wid & 1023;
    const float4* S = g_sorted + (size_t)b * NN;
    const int* SO = g_sorig + (size_t)b * NN;
    const unsigned* BO = g_binoff + b * (ZBINS + 1);
    unsigned long long lt = (1ull << lane) - 1ull;
    unsigned long long* pb0 = qbuf + (w * 2 + 0) * CAPQ;
    unsigned long long* pb1 = qbuf + (w * 2 + 1) * CAPQ;

    #pragma unroll 1
    for (int pp = 0; pp < 4; ++pp) {
        int qr0 = 2 * g + pp * 2048;            // pair: ranks qr0, qr0+1
        float4 qv0 = S[qr0];
        float4 qv1 = S[qr0 + 1];
        int qo0 = SO[qr0];
        int qo1 = SO[qr0 + 1];
        float t0a, t0b, tloa = 0.f, thia = 0.f, tlob = 0.f, thib = 0.f;
        {
            float ta = 0.053f * __expf(qv0.w * (1.0f / 3.0f));
            float tb = 0.053f * __expf(qv1.w * (1.0f / 3.0f));
            t0a = ta > 3.f ? 3.f : ta;
            t0b = tb > 3.f ? 3.f : tb;
        }
        unsigned cnta = 0, cntb = 0;
        bool dna = false, dnb = false;

        for (int attempt = 0; attempt < 40; ++attempt) {
            float zlo = 1e30f, zhi = -1e30f;
            if (!dna) {
                float R = __fsqrt_rn(t0a + 1e-3f) + 1e-3f;
                zlo = fminf(zlo, qv0.z - R); zhi = fmaxf(zhi, qv0.z + R);
            }
            if (!dnb) {
                float R = __fsqrt_rn(t0b + 1e-3f) + 1e-3f;
                zlo = fminf(zlo, qv1.z - R); zhi = fmaxf(zhi, qv1.z + R);
            }
            if (dna && dnb) break;
            int blo = zbin(zlo) - 1; if (blo < 0) blo = 0;
            int bhi = zbin(zhi) + 1; if (bhi > ZBINS - 1) bhi = ZBINS - 1;
            int lo = (int)BO[blo];
            int hi = (int)BO[bhi + 1];

            for (int p = lo; p < hi; p += 64) {
                int jj = p + lane;
                bool inb = jj < hi;
                int j = inb ? jj : hi - 1;
                float4 cc = S[j];
                if (!dna) {
                    float dot = __fmaf_rn(qv0.z, cc.z, __fmaf_rn(qv0.y, cc.y, __fmul_rn(qv0.x, cc.x)));
                    float dist = __fadd_rn(__fmaf_rn(-2.f, dot, qv0.w), cc.w);
                    bool pr = (dist <= t0a) && inb;
                    unsigned long long mask = __ballot(pr);
                    if (mask) {
                        unsigned pos = cnta + (unsigned)__popcll(mask & lt);
                        if (pr && pos < CAPQ) {
                            int corig = SO[j];
                            int db = __float_as_int(dist);
                            unsigned key = (unsigned)db ^ (unsigned)((db >> 31) | 0x80000000);
                            pb0[pos] = ((unsigned long long)key << 32) | (unsigned)corig;
                        }
                        cnta += (unsigned)__popcll(mask);
                    }
                }
                if (!dnb) {
                    float dot = __fmaf_rn(qv1.z, cc.z, __fmaf_rn(qv1.y, cc.y, __fmul_rn(qv1.x, cc.x)));
                    float dist = __fadd_rn(__fmaf_rn(-2.f, dot, qv1.w), cc.w);
                    bool pr = (dist <= t0b) && inb;
                    unsigned long long mask = __ballot(pr);
                    if (mask) {
                        unsigned pos = cntb + (unsigned)__popcll(mask & lt);
                        if (pr && pos < CAPQ) {
                            int corig = SO[j];
                            int db = __float_as_int(dist);
                            unsigned key = (unsigned)db ^ (unsigned)((db >> 31) | 0x80000000);
                            pb1[pos] = ((unsigned long long)key << 32) | (unsigned)corig;
                        }
                        cntb += (unsigned)__popcll(mask);
                    }
                }
            }
            if (!dna) {
                if (cnta < KN) {
                    tloa = t0a;
                    t0a = (thia > 0.f) ? __fsqrt_rn(tloa * thia) : t0a * 2.0f;
                    cnta = 0;
                } else if (cnta > CAPQ) {
                    thia = t0a;
                    t0a = (tloa > 0.f) ? __fsqrt_rn(tloa * thia) : t0a * 0.5f;
                    cnta = 0;
                } else dna = true;
            }
            if (!dnb) {
                if (cntb < KN) {
                    tlob = t0b;
                    t0b = (thib > 0.f) ? __fsqrt_rn(tlob * thib) : t0b * 2.0f;
                    cntb = 0;
                } else if (cntb > CAPQ) {
                    thib = t0b;
                    t0b = (tlob > 0.f) ? __fsqrt_rn(tlob * thib) : t0b * 0.5f;
                    cntb = 0;
                } else dnb = true;
            }
        }

        // ---- selection: counting-rank (CAPQ=64 -> one element per lane) ----
        {
            unsigned tot = cnta > CAPQ ? CAPQ : cnta;
            unsigned long long e0 = ((unsigned)lane < tot) ? pb0[lane] : ~0ull;
            unsigned rank0 = 0;
            for (unsigned jx = 0; jx < tot; ++jx)
                rank0 += (pb0[jx] < e0) ? 1u : 0u;
            if (((unsigned)lane < tot) && rank0 < KN)
                g_idx[(b * NN + qo0) * KN + rank0] = (int)(e0 & 0xffffffffull);
        }
        {
            unsigned tot = cntb > CAPQ ? CAPQ : cntb;
            unsigned long long e0 = ((unsigned)lane < tot) ? pb1[lane] : ~0ull;
            unsigned rank0 = 0;
            for (unsigned jx = 0; jx < tot; ++jx)
                rank0 += (pb1[jx] < e0) ? 1u : 0u;
            if (((unsigned)lane < tot) && rank0 < KN)
                g_idx[(b * NN + qo1) * KN + rank0] = (int)(e0 & 0xffffffffull);
        }
    }
}

// ---------------- kernel 4: gather+max, rel, out = Wh' * rel ----------------
__global__ __launch_bounds__(256) void k_out(const float* __restrict__ Wh,
        float* __restrict__ out) {
    __shared__ float whs[CC * FE];
    int tid = threadIdx.x;
    for (int i = tid; i < CC * FE; i += 256) {
        int c = i >> 5, e = i & 31;
        float s = 0.f;
        #pragma unroll
        for (int m = 0; m < 4; ++m) s += Wh[c * 128 + m * 32 + e];
        whs[i] = s;
    }
    __syncthreads();
    int b = blockIdx.x >> 5;
    int n = ((blockIdx.x & 31) << 8) + tid;
    const int* ip = g_idx + (size_t)(b * NN + n) * KN;
    const float4* f0 = (const float4*)(g_feat0 + (size_t)b * NN * FE);
    float gmax[FE];
    #pragma unroll
    for (int e = 0; e < FE; ++e) gmax[e] = -__builtin_inff();
    for (int k = 0; k < KN; ++k) {
        int id = ip[k] & (NN - 1);      // defensive mask, no-op for valid idx
        const float4* row = f0 + (size_t)id * 8;
        #pragma unroll
        for (int e0 = 0; e0 < 8; ++e0) {
            float4 v = row[e0];
            gmax[e0 * 4 + 0] = fmaxf(gmax[e0 * 4 + 0], v.x);
            gmax[e0 * 4 + 1] = fmaxf(gmax[e0 * 4 + 1], v.y);
            gmax[e0 * 4 + 2] = fmaxf(gmax[e0 * 4 + 2], v.z);
            gmax[e0 * 4 + 3] = fmaxf(gmax[e0 * 4 + 3], v.w);
        }
    }
    const float4* selfr = f0 + (size_t)n * 8;
    float rel[FE];
    #pragma unroll
    for (int e0 = 0; e0 < 8; ++e0) {
        float4 v = selfr[e0];
        rel[e0 * 4 + 0] = gmax[e0 * 4 + 0] - v.x;
        rel[e0 * 4 + 1] = gmax[e0 * 4 + 1] - v.y;
        rel[e0 * 4 + 2] = gmax[e0 * 4 + 2] - v.z;
        rel[e0 * 4 + 3] = gmax[e0 * 4 + 3] - v.w;
    }
    float* op = out + (size_t)b * CC * NN + n;
    for (int c = 0; c < CC; ++c) {
        const float4* w4 = (const float4*)(whs + c * FE);
        float s = 0.f;
        #pragma unroll
        for (int e0 = 0; e0 < 8; ++e0) {
            float4 w = w4[e0];
            s = fmaf(w.x, rel[e0 * 4 + 0], s);
            s = fmaf(w.y, rel[e0 * 4 + 1], s);
            s = fmaf(w.z, rel[e0 * 4 + 2], s);
            s = fmaf(w.w, rel[e0 * 4 + 3], s);
        }
        op[(size_t)c * NN] = s;
    }
}

extern "C" void kernel_launch(void* const* d_in, const int* in_sizes, int n_in,
                              void* d_out, int out_size, void* d_ws, size_t ws_size,
                              hipStream_t stream) {
    const float* xyz   = (const float*)d_in[0];
    const float* feat  = (const float*)d_in[1];
    const float* gamma = (const float*)d_in[2];
    const float* beta  = (const float*)d_in[3];
    const float* Wg    = (const float*)d_in[4];
    const float* Wh    = (const float*)d_in[5];
    float* out = (float*)d_out;
    (void)d_ws; (void)ws_size;

    hipLaunchKernelGGL(k_bnstats, dim3(64),   dim3(1024), 0, stream, feat, gamma, beta);
    hipLaunchKernelGGL(k_zbin,    dim3(8),    dim3(1024), 0, stream, xyz);
    hipLaunchKernelGGL(k_feat0,   dim3(256),  dim3(256),  0, stream, feat, xyz, Wg);
    hipLaunchKernelGGL(k_knn,     dim3(2048), dim3(256),  0, stream);
    hipLaunchKernelGGL(k_out,     dim3(256),  dim3(256),  0, stream, Wh, out);
}

// Round 18
// 216.028 us; speedup vs baseline: 1.6099x; 1.2853x over previous
//
#include <hip/hip_runtime.h>
#include <math.h>

#define BB 8
#define NN 8192
#define CC 64
#define FE 32
#define KN 16
#define CP3 67
#define QPW 8                 // queries per wave (one per cell-rank octile)
#define WPB 4                 // waves per block
#define CAPQ 64               // per-query stack (count-checked => exact)
#define YB 32
#define ZB 32
#define NCELL (YB * ZB)

// Device-global scratch (module .bss). All bytes written every launch before read.
__device__ float g_wsf[128];                  // scale[64], shift[64]
__device__ float g_feat0[BB * NN * FE];       // 8 MB
__device__ int   g_idx[BB * NN * KN];         // 4 MB
__device__ float4 g_sorted[BB * NN];          // cell-sorted {x,y,z,xx}
__device__ int    g_sorig[BB * NN];           // sorted -> original index
__device__ unsigned g_binoff[BB * (NCELL + 1)];

// Identical in k_zbin and k_knn (same source => same bits; monotone).
__device__ __forceinline__ int cbin(float v) {
    int bi = (int)((v + 4.5f) * (32.0f / 9.0f));   // 32 bins over [-4.5,4.5]
    if (bi < 0) bi = 0;
    if (bi > 31) bi = 31;
    return bi;
}
// FROZEN reference xx (verified R5, XLA-CPU FMA contraction)
__device__ __forceinline__ float frz_xx(float x, float y, float z) {
    return __fmaf_rn(z, z, __fmaf_rn(y, y, __fmul_rn(x, x)));
}

// ---------------- kernel 1: BN stats -> scale/shift ----------------
__global__ __launch_bounds__(1024) void k_bnstats(const float* __restrict__ feat,
        const float* __restrict__ gamma, const float* __restrict__ beta) {
    int c = blockIdx.x;
    int tid = threadIdx.x;
    double s = 0.0, s2 = 0.0;
    for (int b = 0; b < BB; ++b) {
        const float* p = feat + ((size_t)(b * CC + c)) * NN;
        for (int n = tid; n < NN; n += 1024) {
            double v = (double)p[n];
            s += v; s2 += v * v;
        }
    }
    __shared__ double sh[1024], sh2[1024];
    sh[tid] = s; sh2[tid] = s2;
    __syncthreads();
    for (int off = 512; off > 0; off >>= 1) {
        if (tid < off) { sh[tid] += sh[tid + off]; sh2[tid] += sh2[tid + off]; }
        __syncthreads();
    }
    if (tid == 0) {
        double inv = 1.0 / (double)(BB * NN);
        double mean = sh[0] * inv;
        double var = sh2[0] * inv - mean * mean;
        float sc = gamma[c] * (float)(1.0 / sqrt(var + (double)1e-5f));
        g_wsf[c] = sc;
        g_wsf[64 + c] = beta[c] - sc * (float)mean;
    }
}

// ---------------- kernel 1b: (y,z) cell binning -----------------------
__global__ __launch_bounds__(1024) void k_zbin(const float* __restrict__ xyz) {
    __shared__ unsigned hist[NCELL];
    __shared__ unsigned scan[NCELL];
    __shared__ unsigned boff[NCELL + 1];
    int b = blockIdx.x;
    int tid = threadIdx.x;
    hist[tid] = 0;
    __syncthreads();
    const float* bx = xyz + (size_t)b * NN * 3;
    for (int n = tid; n < NN; n += 1024) {
        float y = bx[n * 3 + 1], z = bx[n * 3 + 2];
        atomicAdd(&hist[cbin(y) * ZB + cbin(z)], 1u);
    }
    __syncthreads();
    scan[tid] = hist[tid];
    __syncthreads();
    for (int off = 1; off < NCELL; off <<= 1) {
        unsigned add = (tid >= off) ? scan[tid - off] : 0u;
        __syncthreads();
        scan[tid] += add;
        __syncthreads();
    }
    if (tid == 0) boff[0] = 0;
    boff[tid + 1] = scan[tid];
    __syncthreads();
    hist[tid] = 0;                               // reuse as cursors
    g_binoff[b * (NCELL + 1) + tid + 1] = boff[tid + 1];
    if (tid == 0) g_binoff[b * (NCELL + 1)] = 0;
    __syncthreads();
    for (int n = tid; n < NN; n += 1024) {
        const float* p = bx + (size_t)n * 3;
        float x = p[0], y = p[1], z = p[2];
        int cell = cbin(y) * ZB + cbin(z);
        unsigned pos = boff[cell] + atomicAdd(&hist[cell], 1u);
        g_sorted[(size_t)b * NN + pos] = make_float4(x, y, z, frz_xx(x, y, z));
        g_sorig[(size_t)b * NN + pos] = n;
    }
}

// ---------------- kernel 2: feat0 = Wg' * [feat;xyz] + bias0 ----------------
__global__ __launch_bounds__(256) void k_feat0(const float* __restrict__ feat,
        const float* __restrict__ xyz, const float* __restrict__ Wg) {
    __shared__ float wgs[CP3 * FE];
    __shared__ float bias0[FE];
    int tid = threadIdx.x;
    for (int i = tid; i < CP3 * FE; i += 256) {
        int c = i >> 5, e = i & 31;
        float w = Wg[e * CP3 + c];
        if (c < CC) w *= g_wsf[c];
        wgs[c * FE + e] = w;
    }
    if (tid < FE) {
        float sacc = 0.f;
        for (int c = 0; c < CC; ++c) sacc = fmaf(Wg[tid * CP3 + c], g_wsf[64 + c], sacc);
        bias0[tid] = sacc;
    }
    __syncthreads();
    int b = blockIdx.x >> 5;
    int n = ((blockIdx.x & 31) << 8) + tid;
    const float* pz = xyz + ((size_t)(b * NN + n)) * 3;
    float x = pz[0], y = pz[1], z = pz[2];

    float acc[FE];
    #pragma unroll
    for (int e = 0; e < FE; ++e) acc[e] = bias0[e];
    const float* fp = feat + (size_t)b * CC * NN + n;
    for (int c = 0; c < CC; ++c) {
        float v = fp[(size_t)c * NN];
        const float4* w4 = (const float4*)(wgs + c * FE);
        #pragma unroll
        for (int e0 = 0; e0 < 8; ++e0) {
            float4 w = w4[e0];
            acc[e0 * 4 + 0] = fmaf(w.x, v, acc[e0 * 4 + 0]);
            acc[e0 * 4 + 1] = fmaf(w.y, v, acc[e0 * 4 + 1]);
            acc[e0 * 4 + 2] = fmaf(w.z, v, acc[e0 * 4 + 2]);
            acc[e0 * 4 + 3] = fmaf(w.w, v, acc[e0 * 4 + 3]);
        }
    }
    #pragma unroll
    for (int d = 0; d < 3; ++d) {
        float v = (d == 0) ? x : ((d == 1) ? y : z);
        const float4* w4 = (const float4*)(wgs + (CC + d) * FE);
        #pragma unroll
        for (int e0 = 0; e0 < 8; ++e0) {
            float4 w = w4[e0];
            acc[e0 * 4 + 0] = fmaf(w.x, v, acc[e0 * 4 + 0]);
            acc[e0 * 4 + 1] = fmaf(w.y, v, acc[e0 * 4 + 1]);
            acc[e0 * 4 + 2] = fmaf(w.z, v, acc[e0 * 4 + 2]);
            acc[e0 * 4 + 3] = fmaf(w.w, v, acc[e0 * 4 + 3]);
        }
    }
    float4* outp = (float4*)(g_feat0 + ((size_t)(b * NN + n)) * FE);
    #pragma unroll
    for (int e0 = 0; e0 < 8; ++e0)
        outp[e0] = make_float4(acc[e0 * 4 + 0], acc[e0 * 4 + 1], acc[e0 * 4 + 2], acc[e0 * 4 + 3]);
}

// ---------------- kernel 3: 2-D cell-windowed stratified KNN --------------
// FROZEN reference arithmetic (verified R5):
//   dot  = fma(zq,zm, fma(yq,ym, xq*xm))
//   dist = fadd( fma(-2, dot, xx_q), xx_m )
// R18 = R15 stratified autonomous waves + 2-D (y,z) cell pruning: scan only
// cells overlapping [yq-R,yq+R]x[zq-R,zq+R], R = sqrt(t0+1e-3)+1e-3.
// Coverage: a frozen-dist passer has true (cy-yq)^2 <= dist+5e-6 < t0+1e-3
// => |cy-yq| <= R - 4e-4; float rounding of qy+-R (~1e-7) is far inside that
// slack, and cbin is monotone => no bin margin needed. Window superset of
// gate set => cnt = |gate set| (monotone in t0) => R12 bisection proof and
// [16,64] count-check exactness carry unchanged. Selection: counting-rank
// (R13). SO[] loaded only for passers (R15).
__global__ __launch_bounds__(256) void k_knn() {
    __shared__ unsigned long long qbuf[WPB * CAPQ];   // 2 KB
    int tid = threadIdx.x;
    int lane = tid & 63;
    int w = tid >> 6;
    int wid = blockIdx.x * WPB + w;             // 0..8191
    int b = wid >> 10;                          // 1024 waves per batch
    int g = wid & 1023;
    const float4* S = g_sorted + (size_t)b * NN;
    const int* SO = g_sorig + (size_t)b * NN;
    const unsigned* BO = g_binoff + b * (NCELL + 1);
    unsigned long long lt = (1ull << lane) - 1ull;
    unsigned long long* pb = qbuf + w * CAPQ;

    #pragma unroll 1
    for (int i = 0; i < QPW; ++i) {
        int qrank = g + (i << 10);              // stratum i sample
        float4 qv = S[qrank];
        float qx = qv.x, qy = qv.y, qz = qv.z, qxx = qv.w;
        int qorig = SO[qrank];
        float tt = 0.053f * __expf(qxx * (1.0f / 3.0f));   // ~32 expected passers
        float t0 = tt > 3.f ? 3.f : tt;
        float tlo = 0.f, thi = 0.f;             // bracket ends (0 = unset)
        unsigned cnt = 0;

        for (int attempt = 0; attempt < 40; ++attempt) {
            cnt = 0;
            float R = __fsqrt_rn(t0 + 1e-3f) + 1e-3f;
            int ylo = cbin(qy - R), yhi = cbin(qy + R);
            int zlo = cbin(qz - R), zhi = cbin(qz + R);

            for (int yb = ylo; yb <= yhi; ++yb) {
                int lo = (int)BO[yb * ZB + zlo];
                int hi = (int)BO[yb * ZB + zhi + 1];
                for (int p = lo; p < hi; p += 64) {
                    int jj = p + lane;
                    bool inb = jj < hi;
                    int j = inb ? jj : hi - 1;
                    float4 cc = S[j];
                    float dot = __fmaf_rn(qz, cc.z, __fmaf_rn(qy, cc.y, __fmul_rn(qx, cc.x)));
                    float dist = __fadd_rn(__fmaf_rn(-2.f, dot, qxx), cc.w);
                    bool pr = (dist <= t0) && inb;
                    unsigned long long mask = __ballot(pr);
                    if (mask) {
                        unsigned pos = cnt + (unsigned)__popcll(mask & lt);
                        if (pr && pos < CAPQ) {
                            int corig = SO[j];  // loaded only for passers
                            int db = __float_as_int(dist);
                            unsigned key = (unsigned)db ^ (unsigned)((db >> 31) | 0x80000000);
                            pb[pos] = ((unsigned long long)key << 32) | (unsigned)corig;
                        }
                        cnt += (unsigned)__popcll(mask);
                    }
                }
            }
            if (cnt < KN) {
                tlo = t0;
                t0 = (thi > 0.f) ? __fsqrt_rn(tlo * thi) : t0 * 2.0f;
            } else if (cnt > CAPQ) {
                thi = t0;
                t0 = (tlo > 0.f) ? __fsqrt_rn(tlo * thi) : t0 * 0.5f;
            } else break;                        // accepted: stack = all passers
        }

        // ---- selection: counting-rank over the stack (CAPQ=64 -> 1/lane) ----
        unsigned tot = cnt > CAPQ ? CAPQ : cnt;
        unsigned long long e0 = ((unsigned)lane < tot) ? pb[lane] : ~0ull;
        unsigned rank0 = 0;
        for (unsigned jx = 0; jx < tot; ++jx) {
            unsigned long long v = pb[jx];      // uniform addr -> LDS broadcast
            rank0 += (v < e0) ? 1u : 0u;
        }
        if (((unsigned)lane < tot) && rank0 < KN)
            g_idx[(b * NN + qorig) * KN + rank0] = (int)(e0 & 0xffffffffull);
    }
}

// ---------------- kernel 4: gather+max, rel, out = Wh' * rel ----------------
__global__ __launch_bounds__(256) void k_out(const float* __restrict__ Wh,
        float* __restrict__ out) {
    __shared__ float whs[CC * FE];
    int tid = threadIdx.x;
    for (int i = tid; i < CC * FE; i += 256) {
        int c = i >> 5, e = i & 31;
        float s = 0.f;
        #pragma unroll
        for (int m = 0; m < 4; ++m) s += Wh[c * 128 + m * 32 + e];
        whs[i] = s;
    }
    __syncthreads();
    int b = blockIdx.x >> 5;
    int n = ((blockIdx.x & 31) << 8) + tid;
    const int* ip = g_idx + (size_t)(b * NN + n) * KN;
    const float4* f0 = (const float4*)(g_feat0 + (size_t)b * NN * FE);
    float gmax[FE];
    #pragma unroll
    for (int e = 0; e < FE; ++e) gmax[e] = -__builtin_inff();
    for (int k = 0; k < KN; ++k) {
        int id = ip[k] & (NN - 1);      // defensive mask, no-op for valid idx
        const float4* row = f0 + (size_t)id * 8;
        #pragma unroll
        for (int e0 = 0; e0 < 8; ++e0) {
            float4 v = row[e0];
            gmax[e0 * 4 + 0] = fmaxf(gmax[e0 * 4 + 0], v.x);
            gmax[e0 * 4 + 1] = fmaxf(gmax[e0 * 4 + 1], v.y);
            gmax[e0 * 4 + 2] = fmaxf(gmax[e0 * 4 + 2], v.z);
            gmax[e0 * 4 + 3] = fmaxf(gmax[e0 * 4 + 3], v.w);
        }
    }
    const float4* selfr = f0 + (size_t)n * 8;
    float rel[FE];
    #pragma unroll
    for (int e0 = 0; e0 < 8; ++e0) {
        float4 v = selfr[e0];
        rel[e0 * 4 + 0] = gmax[e0 * 4 + 0] - v.x;
        rel[e0 * 4 + 1] = gmax[e0 * 4 + 1] - v.y;
        rel[e0 * 4 + 2] = gmax[e0 * 4 + 2] - v.z;
        rel[e0 * 4 + 3] = gmax[e0 * 4 + 3] - v.w;
    }
    float* op = out + (size_t)b * CC * NN + n;
    for (int c = 0; c < CC; ++c) {
        const float4* w4 = (const float4*)(whs + c * FE);
        float s = 0.f;
        #pragma unroll
        for (int e0 = 0; e0 < 8; ++e0) {
            float4 w = w4[e0];
            s = fmaf(w.x, rel[e0 * 4 + 0], s);
            s = fmaf(w.y, rel[e0 * 4 + 1], s);
            s = fmaf(w.z, rel[e0 * 4 + 2], s);
            s = fmaf(w.w, rel[e0 * 4 + 3], s);
        }
        op[(size_t)c * NN] = s;
    }
}

extern "C" void kernel_launch(void* const* d_in, const int* in_sizes, int n_in,
                              void* d_out, int out_size, void* d_ws, size_t ws_size,
                              hipStream_t stream) {
    const float* xyz   = (const float*)d_in[0];
    const float* feat  = (const float*)d_in[1];
    const float* gamma = (const float*)d_in[2];
    const float* beta  = (const float*)d_in[3];
    const float* Wg    = (const float*)d_in[4];
    const float* Wh    = (const float*)d_in[5];
    float* out = (float*)d_out;
    (void)d_ws; (void)ws_size;

    hipLaunchKernelGGL(k_bnstats, dim3(64),   dim3(1024), 0, stream, feat, gamma, beta);
    hipLaunchKernelGGL(k_zbin,    dim3(8),    dim3(1024), 0, stream, xyz);
    hipLaunchKernelGGL(k_feat0,   dim3(256),  dim3(256),  0, stream, feat, xyz, Wg);
    hipLaunchKernelGGL(k_knn,     dim3(2048), dim3(256),  0, stream);
    hipLaunchKernelGGL(k_out,     dim3(256),  dim3(256),  0, stream, Wh, out);
}

// Round 19
// 209.924 us; speedup vs baseline: 1.6567x; 1.0291x over previous
//
#include <hip/hip_runtime.h>
#include <math.h>

#define BB 8
#define NN 8192
#define CC 64
#define FE 32
#define KN 16
#define CP3 67
#define QPW 8                 // queries per wave (one per cell-rank octile)
#define WPB 4                 // waves per block
#define CAPQ 64               // per-query stack (count-checked => exact)
#define YB 32
#define ZB 32
#define NCELL (YB * ZB)

// Device-global scratch (module .bss). All bytes written every launch before read.
__device__ float g_wsf[128];                  // scale[64], shift[64]
__device__ float g_feat0[BB * NN * FE];       // 8 MB
__device__ int   g_idx[BB * NN * KN];         // 4 MB
__device__ float4 g_sorted[BB * NN];          // cell-sorted {x,y,z,xx}
__device__ int    g_sorig[BB * NN];           // sorted -> original index
__device__ unsigned g_binoff[BB * (NCELL + 1)];

// Identical in k_zbin and k_knn (same source => same bits; monotone).
__device__ __forceinline__ int cbin(float v) {
    int bi = (int)((v + 4.5f) * (32.0f / 9.0f));   // 32 bins over [-4.5,4.5]
    if (bi < 0) bi = 0;
    if (bi > 31) bi = 31;
    return bi;
}
// FROZEN reference xx (verified R5, XLA-CPU FMA contraction)
__device__ __forceinline__ float frz_xx(float x, float y, float z) {
    return __fmaf_rn(z, z, __fmaf_rn(y, y, __fmul_rn(x, x)));
}

// ---------------- kernel 1: BN stats -> scale/shift ----------------
__global__ __launch_bounds__(1024) void k_bnstats(const float* __restrict__ feat,
        const float* __restrict__ gamma, const float* __restrict__ beta) {
    int c = blockIdx.x;
    int tid = threadIdx.x;
    double s = 0.0, s2 = 0.0;
    for (int b = 0; b < BB; ++b) {
        const float* p = feat + ((size_t)(b * CC + c)) * NN;
        for (int n = tid; n < NN; n += 1024) {
            double v = (double)p[n];
            s += v; s2 += v * v;
        }
    }
    __shared__ double sh[1024], sh2[1024];
    sh[tid] = s; sh2[tid] = s2;
    __syncthreads();
    for (int off = 512; off > 0; off >>= 1) {
        if (tid < off) { sh[tid] += sh[tid + off]; sh2[tid] += sh2[tid + off]; }
        __syncthreads();
    }
    if (tid == 0) {
        double inv = 1.0 / (double)(BB * NN);
        double mean = sh[0] * inv;
        double var = sh2[0] * inv - mean * mean;
        float sc = gamma[c] * (float)(1.0 / sqrt(var + (double)1e-5f));
        g_wsf[c] = sc;
        g_wsf[64 + c] = beta[c] - sc * (float)mean;
    }
}

// ---------------- kernel 1b: (y,z) cell binning -----------------------
__global__ __launch_bounds__(1024) void k_zbin(const float* __restrict__ xyz) {
    __shared__ unsigned hist[NCELL];
    __shared__ unsigned scan[NCELL];
    __shared__ unsigned boff[NCELL + 1];
    int b = blockIdx.x;
    int tid = threadIdx.x;
    hist[tid] = 0;
    __syncthreads();
    const float* bx = xyz + (size_t)b * NN * 3;
    for (int n = tid; n < NN; n += 1024) {
        float y = bx[n * 3 + 1], z = bx[n * 3 + 2];
        atomicAdd(&hist[cbin(y) * ZB + cbin(z)], 1u);
    }
    __syncthreads();
    scan[tid] = hist[tid];
    __syncthreads();
    for (int off = 1; off < NCELL; off <<= 1) {
        unsigned add = (tid >= off) ? scan[tid - off] : 0u;
        __syncthreads();
        scan[tid] += add;
        __syncthreads();
    }
    if (tid == 0) boff[0] = 0;
    boff[tid + 1] = scan[tid];
    __syncthreads();
    hist[tid] = 0;                               // reuse as cursors
    g_binoff[b * (NCELL + 1) + tid + 1] = boff[tid + 1];
    if (tid == 0) g_binoff[b * (NCELL + 1)] = 0;
    __syncthreads();
    for (int n = tid; n < NN; n += 1024) {
        const float* p = bx + (size_t)n * 3;
        float x = p[0], y = p[1], z = p[2];
        int cell = cbin(y) * ZB + cbin(z);
        unsigned pos = boff[cell] + atomicAdd(&hist[cell], 1u);
        g_sorted[(size_t)b * NN + pos] = make_float4(x, y, z, frz_xx(x, y, z));
        g_sorig[(size_t)b * NN + pos] = n;
    }
}

// ---------------- kernel 2: feat0 = Wg' * [feat;xyz] + bias0 ----------------
__global__ __launch_bounds__(256) void k_feat0(const float* __restrict__ feat,
        const float* __restrict__ xyz, const float* __restrict__ Wg) {
    __shared__ float wgs[CP3 * FE];
    __shared__ float bias0[FE];
    int tid = threadIdx.x;
    for (int i = tid; i < CP3 * FE; i += 256) {
        int c = i >> 5, e = i & 31;
        float w = Wg[e * CP3 + c];
        if (c < CC) w *= g_wsf[c];
        wgs[c * FE + e] = w;
    }
    if (tid < FE) {
        float sacc = 0.f;
        for (int c = 0; c < CC; ++c) sacc = fmaf(Wg[tid * CP3 + c], g_wsf[64 + c], sacc);
        bias0[tid] = sacc;
    }
    __syncthreads();
    int b = blockIdx.x >> 5;
    int n = ((blockIdx.x & 31) << 8) + tid;
    const float* pz = xyz + ((size_t)(b * NN + n)) * 3;
    float x = pz[0], y = pz[1], z = pz[2];

    float acc[FE];
    #pragma unroll
    for (int e = 0; e < FE; ++e) acc[e] = bias0[e];
    const float* fp = feat + (size_t)b * CC * NN + n;
    for (int c = 0; c < CC; ++c) {
        float v = fp[(size_t)c * NN];
        const float4* w4 = (const float4*)(wgs + c * FE);
        #pragma unroll
        for (int e0 = 0; e0 < 8; ++e0) {
            float4 w = w4[e0];
            acc[e0 * 4 + 0] = fmaf(w.x, v, acc[e0 * 4 + 0]);
            acc[e0 * 4 + 1] = fmaf(w.y, v, acc[e0 * 4 + 1]);
            acc[e0 * 4 + 2] = fmaf(w.z, v, acc[e0 * 4 + 2]);
            acc[e0 * 4 + 3] = fmaf(w.w, v, acc[e0 * 4 + 3]);
        }
    }
    #pragma unroll
    for (int d = 0; d < 3; ++d) {
        float v = (d == 0) ? x : ((d == 1) ? y : z);
        const float4* w4 = (const float4*)(wgs + (CC + d) * FE);
        #pragma unroll
        for (int e0 = 0; e0 < 8; ++e0) {
            float4 w = w4[e0];
            acc[e0 * 4 + 0] = fmaf(w.x, v, acc[e0 * 4 + 0]);
            acc[e0 * 4 + 1] = fmaf(w.y, v, acc[e0 * 4 + 1]);
            acc[e0 * 4 + 2] = fmaf(w.z, v, acc[e0 * 4 + 2]);
            acc[e0 * 4 + 3] = fmaf(w.w, v, acc[e0 * 4 + 3]);
        }
    }
    float4* outp = (float4*)(g_feat0 + ((size_t)(b * NN + n)) * FE);
    #pragma unroll
    for (int e0 = 0; e0 < 8; ++e0)
        outp[e0] = make_float4(acc[e0 * 4 + 0], acc[e0 * 4 + 1], acc[e0 * 4 + 2], acc[e0 * 4 + 3]);
}

// ---------------- kernel 3: 2-D cell-windowed stratified KNN --------------
// FROZEN reference arithmetic (verified R5):
//   dot  = fma(zq,zm, fma(yq,ym, xq*xm))
//   dist = fadd( fma(-2, dot, xx_q), xx_m )
// R19 = R18 + software-prefetch pipeline in the scan: the next 64-candidate
// chunk is loaded into registers BEFORE the current chunk is processed,
// putting 2 loads in flight per wave (R18 counters: VALUBusy 33% ~=
// occupancy -> load-use latency bound, 1 dependent load chain). Evaluation
// ORDER and all gate/selection bits unchanged => identical neighbor sets.
// Proven machinery: cell window coverage (R18), gate+count-check [16,64],
// bracketed geometric bisection (R12), counting-rank (R13), SO[] only for
// passers (R15).
__global__ __launch_bounds__(256) void k_knn() {
    __shared__ unsigned long long qbuf[WPB * CAPQ];   // 2 KB
    int tid = threadIdx.x;
    int lane = tid & 63;
    int w = tid >> 6;
    int wid = blockIdx.x * WPB + w;             // 0..8191
    int b = wid >> 10;                          // 1024 waves per batch
    int g = wid & 1023;
    const float4* S = g_sorted + (size_t)b * NN;
    const int* SO = g_sorig + (size_t)b * NN;
    const unsigned* BO = g_binoff + b * (NCELL + 1);
    unsigned long long lt = (1ull << lane) - 1ull;
    unsigned long long* pb = qbuf + w * CAPQ;

    #pragma unroll 1
    for (int i = 0; i < QPW; ++i) {
        int qrank = g + (i << 10);              // stratum i sample
        float4 qv = S[qrank];
        float qx = qv.x, qy = qv.y, qz = qv.z, qxx = qv.w;
        int qorig = SO[qrank];
        float tt = 0.053f * __expf(qxx * (1.0f / 3.0f));   // ~32 expected passers
        float t0 = tt > 3.f ? 3.f : tt;
        float tlo = 0.f, thi = 0.f;             // bracket ends (0 = unset)
        unsigned cnt = 0;

        for (int attempt = 0; attempt < 40; ++attempt) {
            cnt = 0;
            float R = __fsqrt_rn(t0 + 1e-3f) + 1e-3f;
            int ylo = cbin(qy - R), yhi = cbin(qy + R);
            int zlo = cbin(qz - R), zhi = cbin(qz + R);

            for (int yb = ylo; yb <= yhi; ++yb) {
                int lo = (int)BO[yb * ZB + zlo];
                int hi = (int)BO[yb * ZB + zhi + 1];
                if (lo >= hi) continue;
                int p = lo;
                int jc = p + lane; if (jc > hi - 1) jc = hi - 1;
                float4 cur = S[jc];
                bool inc = (p + lane) < hi;
                while (p < hi) {
                    int pn = p + 64;
                    float4 nxt = cur; int jn = jc; bool inn = false;
                    if (pn < hi) {                       // prefetch next chunk
                        jn = pn + lane; if (jn > hi - 1) jn = hi - 1;
                        nxt = S[jn];
                        inn = (pn + lane) < hi;
                    }
                    float dot = __fmaf_rn(qz, cur.z, __fmaf_rn(qy, cur.y, __fmul_rn(qx, cur.x)));
                    float dist = __fadd_rn(__fmaf_rn(-2.f, dot, qxx), cur.w);
                    bool pr = (dist <= t0) && inc;
                    unsigned long long mask = __ballot(pr);
                    if (mask) {
                        unsigned pos = cnt + (unsigned)__popcll(mask & lt);
                        if (pr && pos < CAPQ) {
                            int corig = SO[jc];  // loaded only for passers
                            int db = __float_as_int(dist);
                            unsigned key = (unsigned)db ^ (unsigned)((db >> 31) | 0x80000000);
                            pb[pos] = ((unsigned long long)key << 32) | (unsigned)corig;
                        }
                        cnt += (unsigned)__popcll(mask);
                    }
                    p = pn; cur = nxt; jc = jn; inc = inn;
                }
            }
            if (cnt < KN) {
                tlo = t0;
                t0 = (thi > 0.f) ? __fsqrt_rn(tlo * thi) : t0 * 2.0f;
            } else if (cnt > CAPQ) {
                thi = t0;
                t0 = (tlo > 0.f) ? __fsqrt_rn(tlo * thi) : t0 * 0.5f;
            } else break;                        // accepted: stack = all passers
        }

        // ---- selection: counting-rank over the stack (CAPQ=64 -> 1/lane) ----
        unsigned tot = cnt > CAPQ ? CAPQ : cnt;
        unsigned long long e0 = ((unsigned)lane < tot) ? pb[lane] : ~0ull;
        unsigned rank0 = 0;
        for (unsigned jx = 0; jx < tot; ++jx) {
            unsigned long long v = pb[jx];      // uniform addr -> LDS broadcast
            rank0 += (v < e0) ? 1u : 0u;
        }
        if (((unsigned)lane < tot) && rank0 < KN)
            g_idx[(b * NN + qorig) * KN + rank0] = (int)(e0 & 0xffffffffull);
    }
}

// ---------------- kernel 4: gather+max, rel, out = Wh' * rel ----------------
__global__ __launch_bounds__(256) void k_out(const float* __restrict__ Wh,
        float* __restrict__ out) {
    __shared__ float whs[CC * FE];
    int tid = threadIdx.x;
    for (int i = tid; i < CC * FE; i += 256) {
        int c = i >> 5, e = i & 31;
        float s = 0.f;
        #pragma unroll
        for (int m = 0; m < 4; ++m) s += Wh[c * 128 + m * 32 + e];
        whs[i] = s;
    }
    __syncthreads();
    int b = blockIdx.x >> 5;
    int n = ((blockIdx.x & 31) << 8) + tid;
    const int* ip = g_idx + (size_t)(b * NN + n) * KN;
    const float4* f0 = (const float4*)(g_feat0 + (size_t)b * NN * FE);
    float gmax[FE];
    #pragma unroll
    for (int e = 0; e < FE; ++e) gmax[e] = -__builtin_inff();
    for (int k = 0; k < KN; ++k) {
        int id = ip[k] & (NN - 1);      // defensive mask, no-op for valid idx
        const float4* row = f0 + (size_t)id * 8;
        #pragma unroll
        for (int e0 = 0; e0 < 8; ++e0) {
            float4 v = row[e0];
            gmax[e0 * 4 + 0] = fmaxf(gmax[e0 * 4 + 0], v.x);
            gmax[e0 * 4 + 1] = fmaxf(gmax[e0 * 4 + 1], v.y);
            gmax[e0 * 4 + 2] = fmaxf(gmax[e0 * 4 + 2], v.z);
            gmax[e0 * 4 + 3] = fmaxf(gmax[e0 * 4 + 3], v.w);
        }
    }
    const float4* selfr = f0 + (size_t)n * 8;
    float rel[FE];
    #pragma unroll
    for (int e0 = 0; e0 < 8; ++e0) {
        float4 v = selfr[e0];
        rel[e0 * 4 + 0] = gmax[e0 * 4 + 0] - v.x;
        rel[e0 * 4 + 1] = gmax[e0 * 4 + 1] - v.y;
        rel[e0 * 4 + 2] = gmax[e0 * 4 + 2] - v.z;
        rel[e0 * 4 + 3] = gmax[e0 * 4 + 3] - v.w;
    }
    float* op = out + (size_t)b * CC * NN + n;
    for (int c = 0; c < CC; ++c) {
        const float4* w4 = (const float4*)(whs + c * FE);
        float s = 0.f;
        #pragma unroll
        for (int e0 = 0; e0 < 8; ++e0) {
            float4 w = w4[e0];
            s = fmaf(w.x, rel[e0 * 4 + 0], s);
            s = fmaf(w.y, rel[e0 * 4 + 1], s);
            s = fmaf(w.z, rel[e0 * 4 + 2], s);
            s = fmaf(w.w, rel[e0 * 4 + 3], s);
        }
        op[(size_t)c * NN] = s;
    }
}

extern "C" void kernel_launch(void* const* d_in, const int* in_sizes, int n_in,
                              void* d_out, int out_size, void* d_ws, size_t ws_size,
                              hipStream_t stream) {
    const float* xyz   = (const float*)d_in[0];
    const float* feat  = (const float*)d_in[1];
    const float* gamma = (const float*)d_in[2];
    const float* beta  = (const float*)d_in[3];
    const float* Wg    = (const float*)d_in[4];
    const float* Wh    = (const float*)d_in[5];
    float* out = (float*)d_out;
    (void)d_ws; (void)ws_size;

    hipLaunchKernelGGL(k_bnstats, dim3(64),   dim3(1024), 0, stream, feat, gamma, beta);
    hipLaunchKernelGGL(k_zbin,    dim3(8),    dim3(1024), 0, stream, xyz);
    hipLaunchKernelGGL(k_feat0,   dim3(256),  dim3(256),  0, stream, feat, xyz, Wg);
    hipLaunchKernelGGL(k_knn,     dim3(2048), dim3(256),  0, stream);
    hipLaunchKernelGGL(k_out,     dim3(256),  dim3(256),  0, stream, Wh, out);
}

// Round 20
// 209.494 us; speedup vs baseline: 1.6601x; 1.0021x over previous
//
#include <hip/hip_runtime.h>
#include <math.h>

#define BB 8
#define NN 8192
#define CC 64
#define FE 32
#define KN 16
#define CP3 67
#define QPW 4                 // queries per wave (one per cell-rank quartile-of-strata)
#define WPB 4                 // waves per block
#define CAPQ 64               // per-query stack (count-checked => exact)
#define YB 32
#define ZB 32
#define NCELL (YB * ZB)

// Device-global scratch (module .bss). All bytes written every launch before read.
__device__ float g_wsf[128];                  // scale[64], shift[64]
__device__ float g_feat0[BB * NN * FE];       // 8 MB
__device__ int   g_idx[BB * NN * KN];         // 4 MB
__device__ float4 g_sorted[BB * NN];          // cell-sorted {x,y,z,xx}
__device__ int    g_sorig[BB * NN];           // sorted -> original index
__device__ unsigned g_binoff[BB * (NCELL + 1)];

// Identical in k_zbin and k_knn (same source => same bits; monotone).
__device__ __forceinline__ int cbin(float v) {
    int bi = (int)((v + 4.5f) * (32.0f / 9.0f));   // 32 bins over [-4.5,4.5]
    if (bi < 0) bi = 0;
    if (bi > 31) bi = 31;
    return bi;
}
// FROZEN reference xx (verified R5, XLA-CPU FMA contraction)
__device__ __forceinline__ float frz_xx(float x, float y, float z) {
    return __fmaf_rn(z, z, __fmaf_rn(y, y, __fmul_rn(x, x)));
}

// ---------------- kernel 1: BN stats -> scale/shift ----------------
__global__ __launch_bounds__(1024) void k_bnstats(const float* __restrict__ feat,
        const float* __restrict__ gamma, const float* __restrict__ beta) {
    int c = blockIdx.x;
    int tid = threadIdx.x;
    double s = 0.0, s2 = 0.0;
    for (int b = 0; b < BB; ++b) {
        const float* p = feat + ((size_t)(b * CC + c)) * NN;
        for (int n = tid; n < NN; n += 1024) {
            double v = (double)p[n];
            s += v; s2 += v * v;
        }
    }
    __shared__ double sh[1024], sh2[1024];
    sh[tid] = s; sh2[tid] = s2;
    __syncthreads();
    for (int off = 512; off > 0; off >>= 1) {
        if (tid < off) { sh[tid] += sh[tid + off]; sh2[tid] += sh2[tid + off]; }
        __syncthreads();
    }
    if (tid == 0) {
        double inv = 1.0 / (double)(BB * NN);
        double mean = sh[0] * inv;
        double var = sh2[0] * inv - mean * mean;
        float sc = gamma[c] * (float)(1.0 / sqrt(var + (double)1e-5f));
        g_wsf[c] = sc;
        g_wsf[64 + c] = beta[c] - sc * (float)mean;
    }
}

// ---------------- kernel 1b: (y,z) cell binning -----------------------
__global__ __launch_bounds__(1024) void k_zbin(const float* __restrict__ xyz) {
    __shared__ unsigned hist[NCELL];
    __shared__ unsigned scan[NCELL];
    __shared__ unsigned boff[NCELL + 1];
    int b = blockIdx.x;
    int tid = threadIdx.x;
    hist[tid] = 0;
    __syncthreads();
    const float* bx = xyz + (size_t)b * NN * 3;
    for (int n = tid; n < NN; n += 1024) {
        float y = bx[n * 3 + 1], z = bx[n * 3 + 2];
        atomicAdd(&hist[cbin(y) * ZB + cbin(z)], 1u);
    }
    __syncthreads();
    scan[tid] = hist[tid];
    __syncthreads();
    for (int off = 1; off < NCELL; off <<= 1) {
        unsigned add = (tid >= off) ? scan[tid - off] : 0u;
        __syncthreads();
        scan[tid] += add;
        __syncthreads();
    }
    if (tid == 0) boff[0] = 0;
    boff[tid + 1] = scan[tid];
    __syncthreads();
    hist[tid] = 0;                               // reuse as cursors
    g_binoff[b * (NCELL + 1) + tid + 1] = boff[tid + 1];
    if (tid == 0) g_binoff[b * (NCELL + 1)] = 0;
    __syncthreads();
    for (int n = tid; n < NN; n += 1024) {
        const float* p = bx + (size_t)n * 3;
        float x = p[0], y = p[1], z = p[2];
        int cell = cbin(y) * ZB + cbin(z);
        unsigned pos = boff[cell] + atomicAdd(&hist[cell], 1u);
        g_sorted[(size_t)b * NN + pos] = make_float4(x, y, z, frz_xx(x, y, z));
        g_sorig[(size_t)b * NN + pos] = n;
    }
}

// ---------------- kernel 2: feat0 = Wg' * [feat;xyz] + bias0 ----------------
__global__ __launch_bounds__(256) void k_feat0(const float* __restrict__ feat,
        const float* __restrict__ xyz, const float* __restrict__ Wg) {
    __shared__ float wgs[CP3 * FE];
    __shared__ float bias0[FE];
    int tid = threadIdx.x;
    for (int i = tid; i < CP3 * FE; i += 256) {
        int c = i >> 5, e = i & 31;
        float w = Wg[e * CP3 + c];
        if (c < CC) w *= g_wsf[c];
        wgs[c * FE + e] = w;
    }
    if (tid < FE) {
        float sacc = 0.f;
        for (int c = 0; c < CC; ++c) sacc = fmaf(Wg[tid * CP3 + c], g_wsf[64 + c], sacc);
        bias0[tid] = sacc;
    }
    __syncthreads();
    int b = blockIdx.x >> 5;
    int n = ((blockIdx.x & 31) << 8) + tid;
    const float* pz = xyz + ((size_t)(b * NN + n)) * 3;
    float x = pz[0], y = pz[1], z = pz[2];

    float acc[FE];
    #pragma unroll
    for (int e = 0; e < FE; ++e) acc[e] = bias0[e];
    const float* fp = feat + (size_t)b * CC * NN + n;
    for (int c = 0; c < CC; ++c) {
        float v = fp[(size_t)c * NN];
        const float4* w4 = (const float4*)(wgs + c * FE);
        #pragma unroll
        for (int e0 = 0; e0 < 8; ++e0) {
            float4 w = w4[e0];
            acc[e0 * 4 + 0] = fmaf(w.x, v, acc[e0 * 4 + 0]);
            acc[e0 * 4 + 1] = fmaf(w.y, v, acc[e0 * 4 + 1]);
            acc[e0 * 4 + 2] = fmaf(w.z, v, acc[e0 * 4 + 2]);
            acc[e0 * 4 + 3] = fmaf(w.w, v, acc[e0 * 4 + 3]);
        }
    }
    #pragma unroll
    for (int d = 0; d < 3; ++d) {
        float v = (d == 0) ? x : ((d == 1) ? y : z);
        const float4* w4 = (const float4*)(wgs + (CC + d) * FE);
        #pragma unroll
        for (int e0 = 0; e0 < 8; ++e0) {
            float4 w = w4[e0];
            acc[e0 * 4 + 0] = fmaf(w.x, v, acc[e0 * 4 + 0]);
            acc[e0 * 4 + 1] = fmaf(w.y, v, acc[e0 * 4 + 1]);
            acc[e0 * 4 + 2] = fmaf(w.z, v, acc[e0 * 4 + 2]);
            acc[e0 * 4 + 3] = fmaf(w.w, v, acc[e0 * 4 + 3]);
        }
    }
    float4* outp = (float4*)(g_feat0 + ((size_t)(b * NN + n)) * FE);
    #pragma unroll
    for (int e0 = 0; e0 < 8; ++e0)
        outp[e0] = make_float4(acc[e0 * 4 + 0], acc[e0 * 4 + 1], acc[e0 * 4 + 2], acc[e0 * 4 + 3]);
}

// ---------------- kernel 3: 2-D cell-windowed stratified KNN --------------
// FROZEN reference arithmetic (verified R5):
//   dot  = fma(zq,zm, fma(yq,ym, xq*xm))
//   dist = fadd( fma(-2, dot, xx_q), xx_m )
// R20 = R19 + finer block granularity for backfill: QPW 8->4 gives 16384
// waves in 4096 blocks = 16 blocks/CU (2x overcommit queue). R19 counters
// (occ 35%, VALUBusy 42%) showed per-wave duty fine but residency draining
// -- grid was exactly-resident (8 blk/CU) with no backfill. Stratification
// retained (qrank = g + i*2048, bijective). All per-query machinery
// byte-identical: cell-window coverage (R18), prefetch pipeline (R19),
// gate+count-check [16,64], bracketed bisection (R12), counting-rank (R13),
// SO[] only for passers (R15) => identical neighbor sets.
__global__ __launch_bounds__(256) void k_knn() {
    __shared__ unsigned long long qbuf[WPB * CAPQ];   // 2 KB
    int tid = threadIdx.x;
    int lane = tid & 63;
    int w = tid >> 6;
    int wid = blockIdx.x * WPB + w;             // 0..16383
    int b = wid >> 11;                          // 2048 waves per batch
    int g = wid & 2047;
    const float4* S = g_sorted + (size_t)b * NN;
    const int* SO = g_sorig + (size_t)b * NN;
    const unsigned* BO = g_binoff + b * (NCELL + 1);
    unsigned long long lt = (1ull << lane) - 1ull;
    unsigned long long* pb = qbuf + w * CAPQ;

    #pragma unroll 1
    for (int i = 0; i < QPW; ++i) {
        int qrank = g + (i << 11);              // stratum i sample
        float4 qv = S[qrank];
        float qx = qv.x, qy = qv.y, qz = qv.z, qxx = qv.w;
        int qorig = SO[qrank];
        float tt = 0.053f * __expf(qxx * (1.0f / 3.0f));   // ~32 expected passers
        float t0 = tt > 3.f ? 3.f : tt;
        float tlo = 0.f, thi = 0.f;             // bracket ends (0 = unset)
        unsigned cnt = 0;

        for (int attempt = 0; attempt < 40; ++attempt) {
            cnt = 0;
            float R = __fsqrt_rn(t0 + 1e-3f) + 1e-3f;
            int ylo = cbin(qy - R), yhi = cbin(qy + R);
            int zlo = cbin(qz - R), zhi = cbin(qz + R);

            for (int yb = ylo; yb <= yhi; ++yb) {
                int lo = (int)BO[yb * ZB + zlo];
                int hi = (int)BO[yb * ZB + zhi + 1];
                if (lo >= hi) continue;
                int p = lo;
                int jc = p + lane; if (jc > hi - 1) jc = hi - 1;
                float4 cur = S[jc];
                bool inc = (p + lane) < hi;
                while (p < hi) {
                    int pn = p + 64;
                    float4 nxt = cur; int jn = jc; bool inn = false;
                    if (pn < hi) {                       // prefetch next chunk
                        jn = pn + lane; if (jn > hi - 1) jn = hi - 1;
                        nxt = S[jn];
                        inn = (pn + lane) < hi;
                    }
                    float dot = __fmaf_rn(qz, cur.z, __fmaf_rn(qy, cur.y, __fmul_rn(qx, cur.x)));
                    float dist = __fadd_rn(__fmaf_rn(-2.f, dot, qxx), cur.w);
                    bool pr = (dist <= t0) && inc;
                    unsigned long long mask = __ballot(pr);
                    if (mask) {
                        unsigned pos = cnt + (unsigned)__popcll(mask & lt);
                        if (pr && pos < CAPQ) {
                            int corig = SO[jc];  // loaded only for passers
                            int db = __float_as_int(dist);
                            unsigned key = (unsigned)db ^ (unsigned)((db >> 31) | 0x80000000);
                            pb[pos] = ((unsigned long long)key << 32) | (unsigned)corig;
                        }
                        cnt += (unsigned)__popcll(mask);
                    }
                    p = pn; cur = nxt; jc = jn; inc = inn;
                }
            }
            if (cnt < KN) {
                tlo = t0;
                t0 = (thi > 0.f) ? __fsqrt_rn(tlo * thi) : t0 * 2.0f;
            } else if (cnt > CAPQ) {
                thi = t0;
                t0 = (tlo > 0.f) ? __fsqrt_rn(tlo * thi) : t0 * 0.5f;
            } else break;                        // accepted: stack = all passers
        }

        // ---- selection: counting-rank over the stack (CAPQ=64 -> 1/lane) ----
        unsigned tot = cnt > CAPQ ? CAPQ : cnt;
        unsigned long long e0 = ((unsigned)lane < tot) ? pb[lane] : ~0ull;
        unsigned rank0 = 0;
        for (unsigned jx = 0; jx < tot; ++jx) {
            unsigned long long v = pb[jx];      // uniform addr -> LDS broadcast
            rank0 += (v < e0) ? 1u : 0u;
        }
        if (((unsigned)lane < tot) && rank0 < KN)
            g_idx[(b * NN + qorig) * KN + rank0] = (int)(e0 & 0xffffffffull);
    }
}

// ---------------- kernel 4: gather+max, rel, out = Wh' * rel ----------------
__global__ __launch_bounds__(256) void k_out(const float* __restrict__ Wh,
        float* __restrict__ out) {
    __shared__ float whs[CC * FE];
    int tid = threadIdx.x;
    for (int i = tid; i < CC * FE; i += 256) {
        int c = i >> 5, e = i & 31;
        float s = 0.f;
        #pragma unroll
        for (int m = 0; m < 4; ++m) s += Wh[c * 128 + m * 32 + e];
        whs[i] = s;
    }
    __syncthreads();
    int b = blockIdx.x >> 5;
    int n = ((blockIdx.x & 31) << 8) + tid;
    const int* ip = g_idx + (size_t)(b * NN + n) * KN;
    const float4* f0 = (const float4*)(g_feat0 + (size_t)b * NN * FE);
    float gmax[FE];
    #pragma unroll
    for (int e = 0; e < FE; ++e) gmax[e] = -__builtin_inff();
    for (int k = 0; k < KN; ++k) {
        int id = ip[k] & (NN - 1);      // defensive mask, no-op for valid idx
        const float4* row = f0 + (size_t)id * 8;
        #pragma unroll
        for (int e0 = 0; e0 < 8; ++e0) {
            float4 v = row[e0];
            gmax[e0 * 4 + 0] = fmaxf(gmax[e0 * 4 + 0], v.x);
            gmax[e0 * 4 + 1] = fmaxf(gmax[e0 * 4 + 1], v.y);
            gmax[e0 * 4 + 2] = fmaxf(gmax[e0 * 4 + 2], v.z);
            gmax[e0 * 4 + 3] = fmaxf(gmax[e0 * 4 + 3], v.w);
        }
    }
    const float4* selfr = f0 + (size_t)n * 8;
    float rel[FE];
    #pragma unroll
    for (int e0 = 0; e0 < 8; ++e0) {
        float4 v = selfr[e0];
        rel[e0 * 4 + 0] = gmax[e0 * 4 + 0] - v.x;
        rel[e0 * 4 + 1] = gmax[e0 * 4 + 1] - v.y;
        rel[e0 * 4 + 2] = gmax[e0 * 4 + 2] - v.z;
        rel[e0 * 4 + 3] = gmax[e0 * 4 + 3] - v.w;
    }
    float* op = out + (size_t)b * CC * NN + n;
    for (int c = 0; c < CC; ++c) {
        const float4* w4 = (const float4*)(whs + c * FE);
        float s = 0.f;
        #pragma unroll
        for (int e0 = 0; e0 < 8; ++e0) {
            float4 w = w4[e0];
            s = fmaf(w.x, rel[e0 * 4 + 0], s);
            s = fmaf(w.y, rel[e0 * 4 + 1], s);
            s = fmaf(w.z, rel[e0 * 4 + 2], s);
            s = fmaf(w.w, rel[e0 * 4 + 3], s);
        }
        op[(size_t)c * NN] = s;
    }
}

extern "C" void kernel_launch(void* const* d_in, const int* in_sizes, int n_in,
                              void* d_out, int out_size, void* d_ws, size_t ws_size,
                              hipStream_t stream) {
    const float* xyz   = (const float*)d_in[0];
    const float* feat  = (const float*)d_in[1];
    const float* gamma = (const float*)d_in[2];
    const float* beta  = (const float*)d_in[3];
    const float* Wg    = (const float*)d_in[4];
    const float* Wh    = (const float*)d_in[5];
    float* out = (float*)d_out;
    (void)d_ws; (void)ws_size;

    hipLaunchKernelGGL(k_bnstats, dim3(64),   dim3(1024), 0, stream, feat, gamma, beta);
    hipLaunchKernelGGL(k_zbin,    dim3(8),    dim3(1024), 0, stream, xyz);
    hipLaunchKernelGGL(k_feat0,   dim3(256),  dim3(256),  0, stream, feat, xyz, Wg);
    hipLaunchKernelGGL(k_knn,     dim3(4096), dim3(256),  0, stream);
    hipLaunchKernelGGL(k_out,     dim3(256),  dim3(256),  0, stream, Wh, out);
}

// Round 21
// 207.340 us; speedup vs baseline: 1.6774x; 1.0104x over previous
//
#include <hip/hip_runtime.h>
#include <math.h>

#define BB 8
#define NN 8192
#define CC 64
#define FE 32
#define KN 16
#define CP3 67
#define QPW 4                 // queries per wave (one per cell-rank stratum)
#define WPB 4                 // waves per block
#define CAPQ 64               // per-query stack (count-checked => exact)
#define YB 32
#define ZB 32
#define NCELL (YB * ZB)

// Device-global scratch (module .bss). All bytes written every launch before read.
__device__ double g_part[BB * CC * 2];        // per-(b,c) BN partial sums
__device__ float g_feat0[BB * NN * FE];       // 8 MB
__device__ int   g_idx[BB * NN * KN];         // 4 MB
__device__ float4 g_sorted[BB * NN];          // cell-sorted {x,y,z,xx}
__device__ int    g_sorig[BB * NN];           // sorted -> original index
__device__ unsigned g_binoff[BB * (NCELL + 1)];

// Identical in k_zbin and k_knn (same source => same bits; monotone).
__device__ __forceinline__ int cbin(float v) {
    int bi = (int)((v + 4.5f) * (32.0f / 9.0f));   // 32 bins over [-4.5,4.5]
    if (bi < 0) bi = 0;
    if (bi > 31) bi = 31;
    return bi;
}
// FROZEN reference xx (verified R5, XLA-CPU FMA contraction)
__device__ __forceinline__ float frz_xx(float x, float y, float z) {
    return __fmaf_rn(z, z, __fmaf_rn(y, y, __fmul_rn(x, x)));
}

// ---------------- kernel 1: BN partial sums, one block per (b,c) ----------
__global__ __launch_bounds__(256) void k_bnstats(const float* __restrict__ feat) {
    int bc = blockIdx.x;                        // b*64 + c, 512 blocks
    const float* p = feat + (size_t)bc * NN;    // coalesced single stream
    int tid = threadIdx.x;
    double s = 0.0, s2 = 0.0;
    for (int n = tid; n < NN; n += 256) {
        double v = (double)p[n];
        s += v; s2 += v * v;
    }
    __shared__ double sh[256], sh2[256];
    sh[tid] = s; sh2[tid] = s2;
    __syncthreads();
    for (int off = 128; off > 0; off >>= 1) {
        if (tid < off) { sh[tid] += sh[tid + off]; sh2[tid] += sh2[tid + off]; }
        __syncthreads();
    }
    if (tid == 0) {
        g_part[bc * 2]     = sh[0];
        g_part[bc * 2 + 1] = sh2[0];
    }
}

// ---------------- kernel 1b: (y,z) cell binning -----------------------
__global__ __launch_bounds__(1024) void k_zbin(const float* __restrict__ xyz) {
    __shared__ unsigned hist[NCELL];
    __shared__ unsigned scan[NCELL];
    __shared__ unsigned boff[NCELL + 1];
    int b = blockIdx.x;
    int tid = threadIdx.x;
    hist[tid] = 0;
    __syncthreads();
    const float* bx = xyz + (size_t)b * NN * 3;
    for (int n = tid; n < NN; n += 1024) {
        float y = bx[n * 3 + 1], z = bx[n * 3 + 2];
        atomicAdd(&hist[cbin(y) * ZB + cbin(z)], 1u);
    }
    __syncthreads();
    scan[tid] = hist[tid];
    __syncthreads();
    for (int off = 1; off < NCELL; off <<= 1) {
        unsigned add = (tid >= off) ? scan[tid - off] : 0u;
        __syncthreads();
        scan[tid] += add;
        __syncthreads();
    }
    if (tid == 0) boff[0] = 0;
    boff[tid + 1] = scan[tid];
    __syncthreads();
    hist[tid] = 0;                               // reuse as cursors
    g_binoff[b * (NCELL + 1) + tid + 1] = boff[tid + 1];
    if (tid == 0) g_binoff[b * (NCELL + 1)] = 0;
    __syncthreads();
    for (int n = tid; n < NN; n += 1024) {
        const float* p = bx + (size_t)n * 3;
        float x = p[0], y = p[1], z = p[2];
        int cell = cbin(y) * ZB + cbin(z);
        unsigned pos = boff[cell] + atomicAdd(&hist[cell], 1u);
        g_sorted[(size_t)b * NN + pos] = make_float4(x, y, z, frz_xx(x, y, z));
        g_sorig[(size_t)b * NN + pos] = n;
    }
}

// ---------------- kernel 2: feat0 = Wg' * [feat;xyz] + bias0 ----------------
// BN finalize folded in: each block reduces the 8 per-batch partials per
// channel (f64) -> scale/shift in LDS; ~1 KB of reads per block, trivial.
__global__ __launch_bounds__(256) void k_feat0(const float* __restrict__ feat,
        const float* __restrict__ xyz, const float* __restrict__ Wg,
        const float* __restrict__ gamma, const float* __restrict__ beta) {
    __shared__ float scs[CC], shs[CC];
    __shared__ float wgs[CP3 * FE];
    __shared__ float bias0[FE];
    int tid = threadIdx.x;
    if (tid < CC) {
        double s = 0.0, s2 = 0.0;
        for (int bb2 = 0; bb2 < BB; ++bb2) {
            s  += g_part[((bb2 << 6) + tid) * 2];
            s2 += g_part[((bb2 << 6) + tid) * 2 + 1];
        }
        double inv = 1.0 / (double)(BB * NN);
        double mean = s * inv;
        double var = s2 * inv - mean * mean;
        float sc = gamma[tid] * (float)(1.0 / sqrt(var + (double)1e-5f));
        scs[tid] = sc;
        shs[tid] = beta[tid] - sc * (float)mean;
    }
    __syncthreads();
    for (int i = tid; i < CP3 * FE; i += 256) {
        int c = i >> 5, e = i & 31;
        float w = Wg[e * CP3 + c];
        if (c < CC) w *= scs[c];
        wgs[c * FE + e] = w;
    }
    if (tid < FE) {
        float sacc = 0.f;
        for (int c = 0; c < CC; ++c) sacc = fmaf(Wg[tid * CP3 + c], shs[c], sacc);
        bias0[tid] = sacc;
    }
    __syncthreads();
    int b = blockIdx.x >> 5;
    int n = ((blockIdx.x & 31) << 8) + tid;
    const float* pz = xyz + ((size_t)(b * NN + n)) * 3;
    float x = pz[0], y = pz[1], z = pz[2];

    float acc[FE];
    #pragma unroll
    for (int e = 0; e < FE; ++e) acc[e] = bias0[e];
    const float* fp = feat + (size_t)b * CC * NN + n;
    for (int c = 0; c < CC; ++c) {
        float v = fp[(size_t)c * NN];
        const float4* w4 = (const float4*)(wgs + c * FE);
        #pragma unroll
        for (int e0 = 0; e0 < 8; ++e0) {
            float4 w = w4[e0];
            acc[e0 * 4 + 0] = fmaf(w.x, v, acc[e0 * 4 + 0]);
            acc[e0 * 4 + 1] = fmaf(w.y, v, acc[e0 * 4 + 1]);
            acc[e0 * 4 + 2] = fmaf(w.z, v, acc[e0 * 4 + 2]);
            acc[e0 * 4 + 3] = fmaf(w.w, v, acc[e0 * 4 + 3]);
        }
    }
    #pragma unroll
    for (int d = 0; d < 3; ++d) {
        float v = (d == 0) ? x : ((d == 1) ? y : z);
        const float4* w4 = (const float4*)(wgs + (CC + d) * FE);
        #pragma unroll
        for (int e0 = 0; e0 < 8; ++e0) {
            float4 w = w4[e0];
            acc[e0 * 4 + 0] = fmaf(w.x, v, acc[e0 * 4 + 0]);
            acc[e0 * 4 + 1] = fmaf(w.y, v, acc[e0 * 4 + 1]);
            acc[e0 * 4 + 2] = fmaf(w.z, v, acc[e0 * 4 + 2]);
            acc[e0 * 4 + 3] = fmaf(w.w, v, acc[e0 * 4 + 3]);
        }
    }
    float4* outp = (float4*)(g_feat0 + ((size_t)(b * NN + n)) * FE);
    #pragma unroll
    for (int e0 = 0; e0 < 8; ++e0)
        outp[e0] = make_float4(acc[e0 * 4 + 0], acc[e0 * 4 + 1], acc[e0 * 4 + 2], acc[e0 * 4 + 3]);
}

// ---------------- kernel 3: 2-D cell-windowed stratified KNN --------------
// FROZEN reference arithmetic (verified R5):
//   dot  = fma(zq,zm, fma(yq,ym, xq*xm))
//   dist = fadd( fma(-2, dot, xx_q), xx_m )
// R21 = R20 + CONTINUOUS CROSS-SEGMENT PREFETCH: the scan is a flattened
// cursor (yb,p,hi); the next chunk's cursor (possibly in a later y-row) is
// advanced FIRST (uniform scalar math + cached BO loads) and its data load
// issued before the current chunk's VALU work. R20 counters (VALUBusy 43%,
// occ 37%): stalls were the ~5 cold L2 loads per window at row-segment
// boundaries that the within-segment prefetch couldn't cover. Chunk visit
// order identical => identical push order => identical neighbor sets.
// Proven machinery: cell-window coverage (R18), gate+count-check [16,64],
// bracketed bisection (R12), counting-rank (R13), SO[] for passers (R15).
__global__ __launch_bounds__(256) void k_knn() {
    __shared__ unsigned long long qbuf[WPB * CAPQ];   // 2 KB
    int tid = threadIdx.x;
    int lane = tid & 63;
    int w = tid >> 6;
    int wid = blockIdx.x * WPB + w;             // 0..16383
    int b = wid >> 11;                          // 2048 waves per batch
    int g = wid & 2047;
    const float4* S = g_sorted + (size_t)b * NN;
    const int* SO = g_sorig + (size_t)b * NN;
    const unsigned* BO = g_binoff + b * (NCELL + 1);
    unsigned long long lt = (1ull << lane) - 1ull;
    unsigned long long* pb = qbuf + w * CAPQ;

    #pragma unroll 1
    for (int i = 0; i < QPW; ++i) {
        int qrank = g + (i << 11);              // stratum i sample
        float4 qv = S[qrank];
        float qx = qv.x, qy = qv.y, qz = qv.z, qxx = qv.w;
        int qorig = SO[qrank];
        float tt = 0.053f * __expf(qxx * (1.0f / 3.0f));   // ~32 expected passers
        float t0 = tt > 3.f ? 3.f : tt;
        float tlo = 0.f, thi = 0.f;             // bracket ends (0 = unset)
        unsigned cnt = 0;

        for (int attempt = 0; attempt < 40; ++attempt) {
            cnt = 0;
            float R = __fsqrt_rn(t0 + 1e-3f) + 1e-3f;
            int ylo = cbin(qy - R), yhi = cbin(qy + R);
            int zlo = cbin(qz - R), zhi = cbin(qz + R);

            // cursor = (yb, p, hi); find first nonempty segment
            int yb = ylo;
            int p = (int)BO[yb * ZB + zlo];
            int hi = (int)BO[yb * ZB + zhi + 1];
            while (p >= hi && yb < yhi) {
                ++yb;
                p = (int)BO[yb * ZB + zlo];
                hi = (int)BO[yb * ZB + zhi + 1];
            }
            bool have = p < hi;
            int jc = 0; float4 cur; bool inc = false;
            if (have) {
                jc = p + lane; if (jc > hi - 1) jc = hi - 1;
                cur = S[jc];
                inc = (p + lane) < hi;
            }
            while (have) {
                // advance cursor (uniform), prefetch next chunk's data
                int yb2 = yb, p2 = p + 64, hi2 = hi;
                while (p2 >= hi2 && yb2 < yhi) {
                    ++yb2;
                    p2 = (int)BO[yb2 * ZB + zlo];
                    hi2 = (int)BO[yb2 * ZB + zhi + 1];
                }
                bool have2 = p2 < hi2;
                int jn = jc; float4 nxt = cur; bool inn = false;
                if (have2) {
                    jn = p2 + lane; if (jn > hi2 - 1) jn = hi2 - 1;
                    nxt = S[jn];                 // in flight during VALU below
                    inn = (p2 + lane) < hi2;
                }
                // process current chunk
                float dot = __fmaf_rn(qz, cur.z, __fmaf_rn(qy, cur.y, __fmul_rn(qx, cur.x)));
                float dist = __fadd_rn(__fmaf_rn(-2.f, dot, qxx), cur.w);
                bool pr = (dist <= t0) && inc;
                unsigned long long mask = __ballot(pr);
                if (mask) {
                    unsigned pos = cnt + (unsigned)__popcll(mask & lt);
                    if (pr && pos < CAPQ) {
                        int corig = SO[jc];      // loaded only for passers
                        int db = __float_as_int(dist);
                        unsigned key = (unsigned)db ^ (unsigned)((db >> 31) | 0x80000000);
                        pb[pos] = ((unsigned long long)key << 32) | (unsigned)corig;
                    }
                    cnt += (unsigned)__popcll(mask);
                }
                yb = yb2; p = p2; hi = hi2; have = have2;
                jc = jn; cur = nxt; inc = inn;
            }
            if (cnt < KN) {
                tlo = t0;
                t0 = (thi > 0.f) ? __fsqrt_rn(tlo * thi) : t0 * 2.0f;
            } else if (cnt > CAPQ) {
                thi = t0;
                t0 = (tlo > 0.f) ? __fsqrt_rn(tlo * thi) : t0 * 0.5f;
            } else break;                        // accepted: stack = all passers
        }

        // ---- selection: counting-rank over the stack (CAPQ=64 -> 1/lane) ----
        unsigned tot = cnt > CAPQ ? CAPQ : cnt;
        unsigned long long e0 = ((unsigned)lane < tot) ? pb[lane] : ~0ull;
        unsigned rank0 = 0;
        for (unsigned jx = 0; jx < tot; ++jx) {
            unsigned long long v = pb[jx];      // uniform addr -> LDS broadcast
            rank0 += (v < e0) ? 1u : 0u;
        }
        if (((unsigned)lane < tot) && rank0 < KN)
            g_idx[(b * NN + qorig) * KN + rank0] = (int)(e0 & 0xffffffffull);
    }
}

// ---------------- kernel 4: gather+max, rel, out = Wh' * rel ----------------
__global__ __launch_bounds__(256) void k_out(const float* __restrict__ Wh,
        float* __restrict__ out) {
    __shared__ float whs[CC * FE];
    int tid = threadIdx.x;
    for (int i = tid; i < CC * FE; i += 256) {
        int c = i >> 5, e = i & 31;
        float s = 0.f;
        #pragma unroll
        for (int m = 0; m < 4; ++m) s += Wh[c * 128 + m * 32 + e];
        whs[i] = s;
    }
    __syncthreads();
    int b = blockIdx.x >> 5;
    int n = ((blockIdx.x & 31) << 8) + tid;
    const int* ip = g_idx + (size_t)(b * NN + n) * KN;
    const float4* f0 = (const float4*)(g_feat0 + (size_t)b * NN * FE);
    float gmax[FE];
    #pragma unroll
    for (int e = 0; e < FE; ++e) gmax[e] = -__builtin_inff();
    for (int k = 0; k < KN; ++k) {
        int id = ip[k] & (NN - 1);      // defensive mask, no-op for valid idx
        const float4* row = f0 + (size_t)id * 8;
        #pragma unroll
        for (int e0 = 0; e0 < 8; ++e0) {
            float4 v = row[e0];
            gmax[e0 * 4 + 0] = fmaxf(gmax[e0 * 4 + 0], v.x);
            gmax[e0 * 4 + 1] = fmaxf(gmax[e0 * 4 + 1], v.y);
            gmax[e0 * 4 + 2] = fmaxf(gmax[e0 * 4 + 2], v.z);
            gmax[e0 * 4 + 3] = fmaxf(gmax[e0 * 4 + 3], v.w);
        }
    }
    const float4* selfr = f0 + (size_t)n * 8;
    float rel[FE];
    #pragma unroll
    for (int e0 = 0; e0 < 8; ++e0) {
        float4 v = selfr[e0];
        rel[e0 * 4 + 0] = gmax[e0 * 4 + 0] - v.x;
        rel[e0 * 4 + 1] = gmax[e0 * 4 + 1] - v.y;
        rel[e0 * 4 + 2] = gmax[e0 * 4 + 2] - v.z;
        rel[e0 * 4 + 3] = gmax[e0 * 4 + 3] - v.w;
    }
    float* op = out + (size_t)b * CC * NN + n;
    for (int c = 0; c < CC; ++c) {
        const float4* w4 = (const float4*)(whs + c * FE);
        float s = 0.f;
        #pragma unroll
        for (int e0 = 0; e0 < 8; ++e0) {
            float4 w = w4[e0];
            s = fmaf(w.x, rel[e0 * 4 + 0], s);
            s = fmaf(w.y, rel[e0 * 4 + 1], s);
            s = fmaf(w.z, rel[e0 * 4 + 2], s);
            s = fmaf(w.w, rel[e0 * 4 + 3], s);
        }
        op[(size_t)c * NN] = s;
    }
}

extern "C" void kernel_launch(void* const* d_in, const int* in_sizes, int n_in,
                              void* d_out, int out_size, void* d_ws, size_t ws_size,
                              hipStream_t stream) {
    const float* xyz   = (const float*)d_in[0];
    const float* feat  = (const float*)d_in[1];
    const float* gamma = (const float*)d_in[2];
    const float* beta  = (const float*)d_in[3];
    const float* Wg    = (const float*)d_in[4];
    const float* Wh    = (const float*)d_in[5];
    float* out = (float*)d_out;
    (void)d_ws; (void)ws_size;

    hipLaunchKernelGGL(k_bnstats, dim3(512),  dim3(256),  0, stream, feat);
    hipLaunchKernelGGL(k_zbin,    dim3(8),    dim3(1024), 0, stream, xyz);
    hipLaunchKernelGGL(k_feat0,   dim3(256),  dim3(256),  0, stream, feat, xyz, Wg, gamma, beta);
    hipLaunchKernelGGL(k_knn,     dim3(4096), dim3(256),  0, stream);
    hipLaunchKernelGGL(k_out,     dim3(256),  dim3(256),  0, stream, Wh, out);
}